// Round 5
// baseline (571.521 us; speedup 1.0000x reference)
//
#include <hip/hip_runtime.h>
#include <hip/hip_bf16.h>

// Problem constants (B=1)
#define CL 2048   // sequence length
#define CD 1024   // hidden
#define CH 16     // heads
#define CHD 64    // head dim
#define NEGS -1e30f

typedef __attribute__((ext_vector_type(8))) short short8;  // 8 x bf16 frag
typedef __attribute__((ext_vector_type(4))) float f32x4;
// One row of scores per WAVE: 32 regs, static indices everywhere.
typedef __attribute__((ext_vector_type(32))) float f32x32;

__device__ __forceinline__ float wave_sum(float x) {
#pragma unroll
  for (int m = 32; m >= 1; m >>= 1) x += __shfl_xor(x, m, 64);
  return x;
}
__device__ __forceinline__ float wave_max(float x) {
#pragma unroll
  for (int m = 32; m >= 1; m >>= 1) x = fmaxf(x, __shfl_xor(x, m, 64));
  return x;
}

__device__ __forceinline__ void split1(float v, short& h, short& l) {
  __hip_bfloat16 bh = __float2bfloat16(v);
  __hip_bfloat16 bl = __float2bfloat16(v - __bfloat162float(bh));
  h = __builtin_bit_cast(short, bh);
  l = __builtin_bit_cast(short, bl);
}
__device__ __forceinline__ unsigned short bf16_bits(float v) {
  __hip_bfloat16 b = __float2bfloat16(v);
  return (unsigned short)__builtin_bit_cast(short, b);
}

// ---- depth-5 tree helpers over f32x32 ----
__device__ __forceinline__ float tree_sum_valid(const f32x32& s) {
  float t[8];
#pragma unroll
  for (int i = 0; i < 8; i++) {
    const float a = s[i]      > -1e29f ? s[i]      : 0.f;
    const float b = s[i + 8]  > -1e29f ? s[i + 8]  : 0.f;
    const float c = s[i + 16] > -1e29f ? s[i + 16] : 0.f;
    const float d = s[i + 24] > -1e29f ? s[i + 24] : 0.f;
    t[i] = (a + b) + (c + d);
  }
#pragma unroll
  for (int i = 0; i < 4; i++) t[i] += t[i + 4];
  t[0] += t[2]; t[1] += t[3];
  return t[0] + t[1];
}
__device__ __forceinline__ float tree_max(const f32x32& s) {
  float t[8];
#pragma unroll
  for (int i = 0; i < 8; i++)
    t[i] = fmaxf(fmaxf(s[i], s[i + 8]), fmaxf(s[i + 16], s[i + 24]));
#pragma unroll
  for (int i = 0; i < 4; i++) t[i] = fmaxf(t[i], t[i + 4]);
  return fmaxf(fmaxf(t[0], t[2]), fmaxf(t[1], t[3]));
}
__device__ __forceinline__ void masked_sc(const f32x32& s, float tau,
                                          float& cs, float& cn) {
  float ts[8], tc[8];
#pragma unroll
  for (int i = 0; i < 8; i++) {
    const float a = s[i], b = s[i + 8], c = s[i + 16], d = s[i + 24];
    ts[i] = ((a > tau ? a : 0.f) + (b > tau ? b : 0.f)) +
            ((c > tau ? c : 0.f) + (d > tau ? d : 0.f));
    tc[i] = ((a > tau ? 1.f : 0.f) + (b > tau ? 1.f : 0.f)) +
            ((c > tau ? 1.f : 0.f) + (d > tau ? 1.f : 0.f));
  }
#pragma unroll
  for (int i = 0; i < 4; i++) { ts[i] += ts[i + 4]; tc[i] += tc[i + 4]; }
  ts[0] += ts[2]; ts[1] += ts[3]; tc[0] += tc[2]; tc[1] += tc[3];
  cs = ts[0] + ts[1];
  cn = tc[0] + tc[1];
}
__device__ __forceinline__ float relu_store_sum(f32x32& s, float ts_) {
  float t[8];
#pragma unroll
  for (int i = 0; i < 8; i++) {
    float a = s[i] - ts_;      a = a > 0.f ? a : 0.f;
    float b = s[i + 8] - ts_;  b = b > 0.f ? b : 0.f;
    float c = s[i + 16] - ts_; c = c > 0.f ? c : 0.f;
    float d = s[i + 24] - ts_; d = d > 0.f ? d : 0.f;
    s[i] = a; s[i + 8] = b; s[i + 16] = c; s[i + 24] = d;
    t[i] = (a + b) + (c + d);
  }
#pragma unroll
  for (int i = 0; i < 4; i++) t[i] += t[i + 4];
  t[0] += t[2]; t[1] += t[3];
  return t[0] + t[1];
}

// Single-row warm-start Michelot. tau* in [max-1, max-1/n] => {s > max-1.000001}
// is a superset of the support; fixpoint count == reference's sort-based
// k_support. Reference quirk kept: tau_star = (FULL masked sum - 1)/cnt.
// Overwrites s with unnormalized p; returns 1/(psum+1e-10).
__device__ __forceinline__ float entmax1(f32x32& s) {
  const float ss = wave_sum(tree_sum_valid(s));
  const float m = wave_max(tree_max(s));
  float tau = m - 1.000001f;
  int cnt = 0;
  for (int it = 0; it < 64; it++) {
    float cs, cn;
    masked_sc(s, tau, cs, cn);
    cs = wave_sum(cs);
    cn = wave_sum(cn);
    const int nc = (int)cn;
    if (nc == cnt) break;   // wave-uniform
    cnt = nc;
    tau = (cs - 1.f) / cn;
  }
  const float ts = (ss - 1.f) / (float)cnt;
  return 1.f / (wave_sum(relu_store_sum(s, ts)) + 1e-10f);
}

// One fused split kernel: fp32 -> bf16 hi/lo planes for x and 4 weights.
__global__ __launch_bounds__(256) void split_all(
    const float* __restrict__ x,  const float* __restrict__ wq,
    const float* __restrict__ wk, const float* __restrict__ wv,
    const float* __restrict__ wo,
    short* __restrict__ xh,  short* __restrict__ xl,
    short* __restrict__ wqh, short* __restrict__ wql,
    short* __restrict__ wkh, short* __restrict__ wkl,
    short* __restrict__ wvh, short* __restrict__ wvl,
    short* __restrict__ woh, short* __restrict__ wol) {
  const int b = blockIdx.x;
  const float* src; short *dh, *dl; int i0;
  if      (b < 2048) { src = x;  dh = xh;  dl = xl;  i0 = b; }
  else if (b < 3072) { src = wq; dh = wqh; dl = wql; i0 = b - 2048; }
  else if (b < 4096) { src = wk; dh = wkh; dl = wkl; i0 = b - 3072; }
  else if (b < 5120) { src = wv; dh = wvh; dl = wvl; i0 = b - 4096; }
  else               { src = wo; dh = woh; dl = wol; i0 = b - 5120; }
  const int i = i0 * 256 + threadIdx.x;
  const float4 v = reinterpret_cast<const float4*>(src)[i];
  const float vv[4] = {v.x, v.y, v.z, v.w};
  short hh[4], ll[4];
#pragma unroll
  for (int e = 0; e < 4; e++) split1(vv[e], hh[e], ll[e]);
  reinterpret_cast<short4*>(dh)[i] = make_short4(hh[0], hh[1], hh[2], hh[3]);
  reinterpret_cast<short4*>(dl)[i] = make_short4(ll[0], ll[1], ll[2], ll[3]);
}

// C[2048,1024] = (Ah+Al) * (B?h+B?l)^T via 3-term split-bf16 MFMA.
// 128x128 tile/WG, LDS-staged BK=32, global_load_lds width=16 staging
// (lane-linear dest: byte off = i*1024 + lane*16). Epilogue: fp32out -> Cf;
// else bf16 hi/lo planes (sel 2 = vT transposed [dim][seq]).
__global__ __launch_bounds__(256, 2) void gemm128_split(
    const short* __restrict__ Ah, const short* __restrict__ Al,
    const short* __restrict__ B0h, const short* __restrict__ B0l,
    const short* __restrict__ B1h, const short* __restrict__ B1l,
    const short* __restrict__ B2h, const short* __restrict__ B2l,
    short* __restrict__ O0h, short* __restrict__ O0l,
    short* __restrict__ O1h, short* __restrict__ O1l,
    short* __restrict__ O2h, short* __restrict__ O2l,
    float* __restrict__ Cf, int fp32out) {
  __shared__ short AhS[128][32], AlS[128][32], BhS[128][32], BlS[128][32];
  const int tid = threadIdx.x, lane = tid & 63, wave = tid >> 6;
  const int l15 = lane & 15, quad = lane >> 4;
  const int sel = blockIdx.x >> 3, nb = blockIdx.x & 7;
  const short* Bh = sel == 0 ? B0h : (sel == 1 ? B1h : B2h);
  const short* Bl = sel == 0 ? B0l : (sel == 1 ? B1l : B2l);
  const int m0 = blockIdx.y * 128, n0 = nb * 128;
  const int wm = (wave >> 1) * 64, wn = (wave & 1) * 64;

  f32x4 acc[4][4];
#pragma unroll
  for (int i = 0; i < 4; i++)
#pragma unroll
    for (int j = 0; j < 4; j++) acc[i][j] = {0.f, 0.f, 0.f, 0.f};

  const short* gsrc = wave == 0 ? Ah : wave == 1 ? Al : wave == 2 ? Bh : Bl;
  short(*ldst)[32] = wave == 0 ? AhS : wave == 1 ? AlS : wave == 2 ? BhS : BlS;
  const int srow0 = (wave < 2) ? m0 : n0;
  const int sr = lane >> 2, skc = (lane & 3) * 8;

  for (int k0 = 0; k0 < CD; k0 += 32) {
#pragma unroll
    for (int i = 0; i < 8; i++) {
      const short* gp =
          gsrc + (size_t)(srow0 + i * 16 + sr) * CD + k0 + skc;
      __builtin_amdgcn_global_load_lds(
          (const __attribute__((address_space(1))) void*)gp,
          (__attribute__((address_space(3))) void*)((char*)&ldst[0][0] + i * 1024),
          16, 0, 0);
    }
    __syncthreads();
    short8 a_h[4], a_l[4], b_h[4], b_l[4];
#pragma unroll
    for (int i = 0; i < 4; i++) {
      a_h[i] = *reinterpret_cast<const short8*>(&AhS[wm + i * 16 + l15][quad * 8]);
      a_l[i] = *reinterpret_cast<const short8*>(&AlS[wm + i * 16 + l15][quad * 8]);
      b_h[i] = *reinterpret_cast<const short8*>(&BhS[wn + i * 16 + l15][quad * 8]);
      b_l[i] = *reinterpret_cast<const short8*>(&BlS[wn + i * 16 + l15][quad * 8]);
    }
#pragma unroll
    for (int im = 0; im < 4; im++)
#pragma unroll
      for (int in = 0; in < 4; in++) {
        acc[im][in] = __builtin_amdgcn_mfma_f32_16x16x32_bf16(a_h[im], b_l[in], acc[im][in], 0, 0, 0);
        acc[im][in] = __builtin_amdgcn_mfma_f32_16x16x32_bf16(a_l[im], b_h[in], acc[im][in], 0, 0, 0);
        acc[im][in] = __builtin_amdgcn_mfma_f32_16x16x32_bf16(a_h[im], b_h[in], acc[im][in], 0, 0, 0);
      }
    __syncthreads();
  }

#pragma unroll
  for (int im = 0; im < 4; im++)
#pragma unroll
    for (int in = 0; in < 4; in++)
#pragma unroll
      for (int r = 0; r < 4; r++) {
        const int mr = m0 + wm + im * 16 + quad * 4 + r;
        const int nc = n0 + wn + in * 16 + l15;
        const float val = acc[im][in][r];
        if (fp32out) {
          Cf[(size_t)mr * CD + nc] = val;
        } else {
          short sh, sl;
          split1(val, sh, sl);
          if (sel == 0) {
            O0h[(size_t)mr * CD + nc] = sh; O0l[(size_t)mr * CD + nc] = sl;
          } else if (sel == 1) {
            O1h[(size_t)mr * CD + nc] = sh; O1l[(size_t)mr * CD + nc] = sl;
          } else {  // vT[dim][seq]
            O2h[(size_t)nc * CL + mr] = sh; O2l[(size_t)nc * CL + mr] = sl;
          }
        }
      }
}

// R12 (resubmitted R13 — R12 bench was an infra failure, never measured):
// 8-wave WG (512 thr), 8 q-rows per WG, grid (256,16).
// Rationale (R3 counters): attn16 at 346us had MfmaUtil 3% / VALUBusy 32% /
// Occupancy 34.5% -> latency-bound with ONE 16-wave block/CU resident (unified
// regs ~70+/wave quantize 16-wave WGs to 4 waves/SIMD). 8-wave WGs pack 3
// WGs/CU (6 waves/SIMD at ~75 regs) -> independent WGs overlap Michelot (VALU)
// with MFMA/LDS phases. M=16 MFMAs carry 8 valid rows (MFMA pipe is 3% busy -
// waste is free). quad<2 guards scatter/reduce to rows 0..7; Ptile pad rows
// 8..15 zeroed once (PV contribution exactly 0). Q-frag overhang at qb=255
// reads qlp (finite) and lands only in discarded C rows. K/V overflow extents
// identical to the 16-row version (benign, into adjacent workspace planes).
// s_setprio(1) around MFMA clusters (m191: helps when co-resident WGs sit at
// different phases). Double-buffered Stile/Ptile: ONE barrier per tile.
__global__ __launch_bounds__(512, 4) void attn8(
    const short* __restrict__ qh, const short* __restrict__ ql,
    const short* __restrict__ kh, const short* __restrict__ kl,
    const short* __restrict__ vhT, const short* __restrict__ vlT,
    short* __restrict__ oh, short* __restrict__ ol) {
  __shared__ float Stile[2][8][260];            // 16.6 KB
  __shared__ unsigned short Ptile[2][16][264];  // 16.5 KB (rows 8..15 = zero pad)
  __shared__ float Rtile[2][8][68];             // 4.25 KB partial PV (2 kgroups)
  __shared__ float invS[8];                     // total ~38 KB -> 3-4 WGs/CU

  const int tid = threadIdx.x, lane = tid & 63, wave = tid >> 6;  // wave 0..7
  const int l15 = lane & 15, quad = lane >> 4;
  const int bx = blockIdx.x;
  const int qb = (bx & 1) ? (255 - (bx >> 1)) : (bx >> 1);  // heavy+light mix
  const int h = blockIdx.y, q0 = qb * 8, col0 = h * CHD;
  const int grow = q0 + wave;                 // this wave's global q-row
  const int ntiles = (q0 + 263) >> 8;         // 256-col tiles covering 0..q0+7
  const int rmax = q0 + 7;                    // last valid column in this block

  // Q A-frags rows q0..q0+15 (l15): rows 8..15 belong to the next block (or,
  // for qb=255, overrun into qlp - finite bf16); their C rows are discarded.
  short8 a_h[2], a_l[2];
  {
    const size_t qbase = (size_t)(q0 + l15) * CD + col0 + quad * 8;
#pragma unroll
    for (int kb = 0; kb < 2; kb++) {
      a_h[kb] = *reinterpret_cast<const short8*>(qh + qbase + kb * 32);
      a_l[kb] = *reinterpret_cast<const short8*>(ql + qbase + kb * 32);
    }
  }

  // Zero Ptile pad rows 8..15, both buffers (wave w owns row w+8). Ordered
  // before any phase-3 read by the phase-1/3 barriers.
#pragma unroll
  for (int tt = 0; tt < 4; tt++) {
    Ptile[0][wave + 8][64 * tt + lane] = 0;
    Ptile[1][wave + 8][64 * tt + lane] = 0;
  }

  f32x32 s;
#pragma unroll
  for (int t = 0; t < 32; t++) s[t] = NEGS;

  // ---- Phase 1: scores. Wave w owns 32 cols per 256-tile (two 16-col blocks).
#pragma unroll
  for (int jt = 0; jt < 8; jt++) {
    if (jt < ntiles) {                        // WG-uniform
      const int j0 = jt * 256;
      const int buf = jt & 1;
#pragma unroll
      for (int cb = 0; cb < 2; cb++) {
        const int c0 = 32 * wave + 16 * cb;   // tile-local col base
        if (j0 + c0 <= rmax) {                // wave-uniform causal-tail skip
          const size_t kbase = (size_t)(j0 + c0 + l15) * CD + col0 + quad * 8;
          f32x4 c = {0.f, 0.f, 0.f, 0.f};
          __builtin_amdgcn_s_setprio(1);
#pragma unroll
          for (int kb = 0; kb < 2; kb++) {
            const short8 b_h = *reinterpret_cast<const short8*>(kh + kbase + kb * 32);
            const short8 b_l = *reinterpret_cast<const short8*>(kl + kbase + kb * 32);
            c = __builtin_amdgcn_mfma_f32_16x16x32_bf16(a_l[kb], b_l, c, 0, 0, 0);
            c = __builtin_amdgcn_mfma_f32_16x16x32_bf16(a_h[kb], b_l, c, 0, 0, 0);
            c = __builtin_amdgcn_mfma_f32_16x16x32_bf16(a_l[kb], b_h, c, 0, 0, 0);
            c = __builtin_amdgcn_mfma_f32_16x16x32_bf16(a_h[kb], b_h, c, 0, 0, 0);
          }
          __builtin_amdgcn_s_setprio(0);
          // C: col(seq in tile) = c0 + l15, row(q) = quad*4 + r (keep rows 0..7)
#pragma unroll
          for (int r = 0; r < 4; r++)
            if (quad < 2) Stile[buf][quad * 4 + r][c0 + l15] = c[r];
        }
      }
      __syncthreads();
      // Gather MY row: lane ll owns cols j0 + 64*tt + ll (2-way = free)
#pragma unroll
      for (int tt = 0; tt < 4; tt++) {
        if (j0 + 64 * tt <= grow) {           // wave-uniform group-valid check
          const int col = j0 + 64 * tt + lane;
          const float v = Stile[buf][wave][64 * tt + lane] * 0.125f;  // exact
          s[jt * 4 + tt] = (col <= grow) ? v : NEGS;
        }
      }
      // no trailing barrier: next scatter targets the other buffer
    }
  }

  // ---- Phase 2: entmax, 8 rows fully parallel (one wave each) ----
  const float inv = entmax1(s);
  if (lane == 0) invS[wave] = inv;

  // ---- Phase 3: P @ V. wave = (kgroup wave>>2 in {0,1}, dim-block wave&3) ----
  f32x4 acc = {0.f, 0.f, 0.f, 0.f};
  const int db = wave & 3, kcg = wave >> 2;
#pragma unroll
  for (int jt = 0; jt < 8; jt++) {
    if (jt < ntiles) {
      const int j0 = jt * 256;
      const int buf = jt & 1;
#pragma unroll
      for (int tt = 0; tt < 4; tt++)
        if (j0 + 64 * tt <= rmax)             // skip groups no chunk reads
          Ptile[buf][wave][64 * tt + lane] = bf16_bits(s[jt * 4 + tt]);
      __syncthreads();
      const size_t vrowbase = (size_t)(col0 + 16 * db + l15) * CL + j0;
#pragma unroll
      for (int t2 = 0; t2 < 4; t2++) {
        const int kc = 2 * t2 + kcg;          // interleaved: balanced under tail
        if (j0 + kc * 32 <= rmax) {           // wave-uniform causal-tail skip
          const short8 pa =
              *reinterpret_cast<const short8*>(&Ptile[buf][l15][kc * 32 + quad * 8]);
          const size_t vb = vrowbase + kc * 32 + quad * 8;
          const short8 vbh = *reinterpret_cast<const short8*>(vhT + vb);
          const short8 vbl = *reinterpret_cast<const short8*>(vlT + vb);
          __builtin_amdgcn_s_setprio(1);
          acc = __builtin_amdgcn_mfma_f32_16x16x32_bf16(pa, vbl, acc, 0, 0, 0);
          acc = __builtin_amdgcn_mfma_f32_16x16x32_bf16(pa, vbh, acc, 0, 0, 0);
          __builtin_amdgcn_s_setprio(0);
        }
      }
      // no trailing barrier: next P-write targets the other buffer
    }
  }

  // ---- Cross-wave K-group reduce + epilogue (rows 0..7 only) ----
#pragma unroll
  for (int r = 0; r < 4; r++)
    if (quad < 2) Rtile[kcg][quad * 4 + r][db * 16 + l15] = acc[r];
  __syncthreads();
  if (wave < 4) {  // wave u handles dim-block u for rows 0..7
#pragma unroll
    for (int r = 0; r < 4; r++) {
      if (quad < 2) {
        const int row = quad * 4 + r;
        float o = Rtile[0][row][wave * 16 + l15] + Rtile[1][row][wave * 16 + l15];
        o *= invS[row];
        short sh, sl;
        split1(o, sh, sl);
        const size_t oidx = (size_t)(q0 + row) * CD + col0 + wave * 16 + l15;
        oh[oidx] = sh;
        ol[oidx] = sl;
      }
    }
  }
}

extern "C" void kernel_launch(void* const* d_in, const int* in_sizes, int n_in,
                              void* d_out, int out_size, void* d_ws, size_t ws_size,
                              hipStream_t stream) {
  const float* x  = (const float*)d_in[0];
  const float* Wq = (const float*)d_in[1];
  const float* Wk = (const float*)d_in[2];
  const float* Wv = (const float*)d_in[3];
  const float* Wo = (const float*)d_in[4];
  float* out = (float*)d_out;

  // Workspace layout (56 MB total)
  char* ws = (char*)d_ws;
  short* xh  = (short*)(ws + (0ull  << 20));
  short* xl  = (short*)(ws + (4ull  << 20));
  short* wqh = (short*)(ws + (8ull  << 20));
  short* wql = (short*)(ws + (10ull << 20));
  short* wkh = (short*)(ws + (12ull << 20));
  short* wkl = (short*)(ws + (14ull << 20));
  short* wvh = (short*)(ws + (16ull << 20));
  short* wvl = (short*)(ws + (18ull << 20));
  short* woh = (short*)(ws + (20ull << 20));
  short* wol = (short*)(ws + (22ull << 20));
  short* qhp = (short*)(ws + (24ull << 20));
  short* qlp = (short*)(ws + (28ull << 20));
  short* khp = (short*)(ws + (32ull << 20));
  short* klp = (short*)(ws + (36ull << 20));
  short* vhT = (short*)(ws + (40ull << 20));
  short* vlT = (short*)(ws + (44ull << 20));
  short* ohp = (short*)(ws + (48ull << 20));
  short* olp = (short*)(ws + (52ull << 20));

  split_all<<<6144, 256, 0, stream>>>(x, Wq, Wk, Wv, Wo,
                                      xh, xl, wqh, wql, wkh, wkl,
                                      wvh, wvl, woh, wol);

  // Fused QKV: grid.x = 24, sel = x>>3 -> q/k planes row-major, vT transposed
  gemm128_split<<<dim3(24, CL / 128), 256, 0, stream>>>(
      xh, xl, wqh, wql, wkh, wkl, wvh, wvl,
      qhp, qlp, khp, klp, vhT, vlT, nullptr, 0);

  attn8<<<dim3(CL / 8, CH), 512, 0, stream>>>(
      qhp, qlp, khp, klp, vhT, vlT, ohp, olp);

  // Wo: grid.x = 8 (sel = 0), fp32 out
  gemm128_split<<<dim3(8, CL / 128), 256, 0, stream>>>(
      ohp, olp, woh, wol, woh, wol, woh, wol,
      ohp, olp, ohp, olp, ohp, olp, out, 1);
}

// Round 9
// 505.803 us; speedup vs baseline: 1.1299x; 1.1299x over previous
//
#include <hip/hip_runtime.h>
#include <hip/hip_bf16.h>

// Problem constants (B=1)
#define CL 2048   // sequence length
#define CD 1024   // hidden
#define CH 16     // heads
#define CHD 64    // head dim
#define NEGS -1e30f

typedef __attribute__((ext_vector_type(8))) short short8;  // 8 x bf16 frag
typedef __attribute__((ext_vector_type(4))) float f32x4;
// One row of scores per WAVE: 32 regs, static indices everywhere.
typedef __attribute__((ext_vector_type(32))) float f32x32;

// R14/R16: DPP-based wave reductions. R3/R5 profiles: Michelot's two shfl_xor
// reductions per iteration = 12 serial ds_bpermute (~600 cy stall/iter) at
// ~20-30 iters/row -> dominant stall. rocPRIM ladder: row_shr 1/2/4/8 +
// row_bcast15/31, then readlane 63 -> SGPR (wave-uniform, scalar break test).
// R16 fix: dpp_ctrl MUST be an integer-constant-expression at the frontend
// (pre-inline) -> non-type template parameter (R7 compile fail as fn arg).
// Identity handling: add uses old=0 + bound_ctrl=1 (invalid lanes -> 0);
// max uses old=-inf + bound_ctrl=0 (invalid lanes -> old = -inf).
template <int CTRL>
__device__ __forceinline__ float dpp_add_step(float x) {
  int v = __builtin_amdgcn_update_dpp(0, __builtin_bit_cast(int, x),
                                      CTRL, 0xf, 0xf, true);
  return x + __builtin_bit_cast(float, v);
}
template <int CTRL>
__device__ __forceinline__ float dpp_max_step(float x) {
  int v = __builtin_amdgcn_update_dpp((int)0xff800000, __builtin_bit_cast(int, x),
                                      CTRL, 0xf, 0xf, false);
  return fmaxf(x, __builtin_bit_cast(float, v));
}
__device__ __forceinline__ float wave_sum(float x) {
  x = dpp_add_step<0x111>(x);  // row_shr:1
  x = dpp_add_step<0x112>(x);  // row_shr:2
  x = dpp_add_step<0x114>(x);  // row_shr:4
  x = dpp_add_step<0x118>(x);  // row_shr:8
  x = dpp_add_step<0x142>(x);  // row_bcast:15
  x = dpp_add_step<0x143>(x);  // row_bcast:31
  return __builtin_bit_cast(float,
      __builtin_amdgcn_readlane(__builtin_bit_cast(int, x), 63));
}
__device__ __forceinline__ float wave_max(float x) {
  x = dpp_max_step<0x111>(x);
  x = dpp_max_step<0x112>(x);
  x = dpp_max_step<0x114>(x);
  x = dpp_max_step<0x118>(x);
  x = dpp_max_step<0x142>(x);
  x = dpp_max_step<0x143>(x);
  return __builtin_bit_cast(float,
      __builtin_amdgcn_readlane(__builtin_bit_cast(int, x), 63));
}

__device__ __forceinline__ void split1(float v, short& h, short& l) {
  __hip_bfloat16 bh = __float2bfloat16(v);
  __hip_bfloat16 bl = __float2bfloat16(v - __bfloat162float(bh));
  h = __builtin_bit_cast(short, bh);
  l = __builtin_bit_cast(short, bl);
}
__device__ __forceinline__ unsigned short bf16_bits(float v) {
  __hip_bfloat16 b = __float2bfloat16(v);
  return (unsigned short)__builtin_bit_cast(short, b);
}

// ---- depth-5 tree helpers over f32x32 ----
__device__ __forceinline__ float tree_sum_valid(const f32x32& s) {
  float t[8];
#pragma unroll
  for (int i = 0; i < 8; i++) {
    const float a = s[i]      > -1e29f ? s[i]      : 0.f;
    const float b = s[i + 8]  > -1e29f ? s[i + 8]  : 0.f;
    const float c = s[i + 16] > -1e29f ? s[i + 16] : 0.f;
    const float d = s[i + 24] > -1e29f ? s[i + 24] : 0.f;
    t[i] = (a + b) + (c + d);
  }
#pragma unroll
  for (int i = 0; i < 4; i++) t[i] += t[i + 4];
  t[0] += t[2]; t[1] += t[3];
  return t[0] + t[1];
}
__device__ __forceinline__ float tree_max(const f32x32& s) {
  float t[8];
#pragma unroll
  for (int i = 0; i < 8; i++)
    t[i] = fmaxf(fmaxf(s[i], s[i + 8]), fmaxf(s[i + 16], s[i + 24]));
#pragma unroll
  for (int i = 0; i < 4; i++) t[i] = fmaxf(t[i], t[i + 4]);
  return fmaxf(fmaxf(t[0], t[2]), fmaxf(t[1], t[3]));
}
__device__ __forceinline__ void masked_sc(const f32x32& s, float tau,
                                          float& cs, float& cn) {
  float ts[8], tc[8];
#pragma unroll
  for (int i = 0; i < 8; i++) {
    const float a = s[i], b = s[i + 8], c = s[i + 16], d = s[i + 24];
    ts[i] = ((a > tau ? a : 0.f) + (b > tau ? b : 0.f)) +
            ((c > tau ? c : 0.f) + (d > tau ? d : 0.f));
    tc[i] = ((a > tau ? 1.f : 0.f) + (b > tau ? 1.f : 0.f)) +
            ((c > tau ? 1.f : 0.f) + (d > tau ? 1.f : 0.f));
  }
#pragma unroll
  for (int i = 0; i < 4; i++) { ts[i] += ts[i + 4]; tc[i] += tc[i + 4]; }
  ts[0] += ts[2]; ts[1] += ts[3]; tc[0] += tc[2]; tc[1] += tc[3];
  cs = ts[0] + ts[1];
  cn = tc[0] + tc[1];
}
__device__ __forceinline__ float relu_store_sum(f32x32& s, float ts_) {
  float t[8];
#pragma unroll
  for (int i = 0; i < 8; i++) {
    float a = s[i] - ts_;      a = a > 0.f ? a : 0.f;
    float b = s[i + 8] - ts_;  b = b > 0.f ? b : 0.f;
    float c = s[i + 16] - ts_; c = c > 0.f ? c : 0.f;
    float d = s[i + 24] - ts_; d = d > 0.f ? d : 0.f;
    s[i] = a; s[i + 8] = b; s[i + 16] = c; s[i + 24] = d;
    t[i] = (a + b) + (c + d);
  }
#pragma unroll
  for (int i = 0; i < 4; i++) t[i] += t[i + 4];
  t[0] += t[2]; t[1] += t[3];
  return t[0] + t[1];
}

// Single-row warm-start Michelot. tau* in [max-1, max-1/n] => {s > max-1.000001}
// is a superset of the support; fixpoint count == reference's sort-based
// k_support. Reference quirk kept: tau_star = (FULL masked sum - 1)/cnt.
// Overwrites s with unnormalized p; returns 1/(psum+1e-10).
__device__ __forceinline__ float entmax1(f32x32& s) {
  const float ss = wave_sum(tree_sum_valid(s));
  const float m = wave_max(tree_max(s));
  float tau = m - 1.000001f;
  int cnt = 0;
  for (int it = 0; it < 64; it++) {
    float cs, cn;
    masked_sc(s, tau, cs, cn);
    cs = wave_sum(cs);
    cn = wave_sum(cn);
    const int nc = (int)cn;
    if (nc == cnt) break;   // wave-uniform (SGPR after readlane)
    cnt = nc;
    tau = (cs - 1.f) / cn;
  }
  const float ts = (ss - 1.f) / (float)cnt;
  return 1.f / (wave_sum(relu_store_sum(s, ts)) + 1e-10f);
}

// One fused split kernel: fp32 -> bf16 hi/lo planes for x and 4 weights.
__global__ __launch_bounds__(256) void split_all(
    const float* __restrict__ x,  const float* __restrict__ wq,
    const float* __restrict__ wk, const float* __restrict__ wv,
    const float* __restrict__ wo,
    short* __restrict__ xh,  short* __restrict__ xl,
    short* __restrict__ wqh, short* __restrict__ wql,
    short* __restrict__ wkh, short* __restrict__ wkl,
    short* __restrict__ wvh, short* __restrict__ wvl,
    short* __restrict__ woh, short* __restrict__ wol) {
  const int b = blockIdx.x;
  const float* src; short *dh, *dl; int i0;
  if      (b < 2048) { src = x;  dh = xh;  dl = xl;  i0 = b; }
  else if (b < 3072) { src = wq; dh = wqh; dl = wql; i0 = b - 2048; }
  else if (b < 4096) { src = wk; dh = wkh; dl = wkl; i0 = b - 3072; }
  else if (b < 5120) { src = wv; dh = wvh; dl = wvl; i0 = b - 4096; }
  else               { src = wo; dh = woh; dl = wol; i0 = b - 5120; }
  const int i = i0 * 256 + threadIdx.x;
  const float4 v = reinterpret_cast<const float4*>(src)[i];
  const float vv[4] = {v.x, v.y, v.z, v.w};
  short hh[4], ll[4];
#pragma unroll
  for (int e = 0; e < 4; e++) split1(vv[e], hh[e], ll[e]);
  reinterpret_cast<short4*>(dh)[i] = make_short4(hh[0], hh[1], hh[2], hh[3]);
  reinterpret_cast<short4*>(dl)[i] = make_short4(ll[0], ll[1], ll[2], ll[3]);
}

// C[2048,1024] = (Ah+Al) * (B?h+B?l)^T via 3-term split-bf16 MFMA.
// 128x128 tile/WG, LDS-staged BK=32, global_load_lds width=16 staging
// (lane-linear dest: byte off = i*1024 + lane*16). Epilogue: fp32out -> Cf;
// else bf16 hi/lo planes (sel 2 = vT transposed [dim][seq]).
__global__ __launch_bounds__(256, 2) void gemm128_split(
    const short* __restrict__ Ah, const short* __restrict__ Al,
    const short* __restrict__ B0h, const short* __restrict__ B0l,
    const short* __restrict__ B1h, const short* __restrict__ B1l,
    const short* __restrict__ B2h, const short* __restrict__ B2l,
    short* __restrict__ O0h, short* __restrict__ O0l,
    short* __restrict__ O1h, short* __restrict__ O1l,
    short* __restrict__ O2h, short* __restrict__ O2l,
    float* __restrict__ Cf, int fp32out) {
  __shared__ short AhS[128][32], AlS[128][32], BhS[128][32], BlS[128][32];
  const int tid = threadIdx.x, lane = tid & 63, wave = tid >> 6;
  const int l15 = lane & 15, quad = lane >> 4;
  const int sel = blockIdx.x >> 3, nb = blockIdx.x & 7;
  const short* Bh = sel == 0 ? B0h : (sel == 1 ? B1h : B2h);
  const short* Bl = sel == 0 ? B0l : (sel == 1 ? B1l : B2l);
  const int m0 = blockIdx.y * 128, n0 = nb * 128;
  const int wm = (wave >> 1) * 64, wn = (wave & 1) * 64;

  f32x4 acc[4][4];
#pragma unroll
  for (int i = 0; i < 4; i++)
#pragma unroll
    for (int j = 0; j < 4; j++) acc[i][j] = {0.f, 0.f, 0.f, 0.f};

  const short* gsrc = wave == 0 ? Ah : wave == 1 ? Al : wave == 2 ? Bh : Bl;
  short(*ldst)[32] = wave == 0 ? AhS : wave == 1 ? AlS : wave == 2 ? BhS : BlS;
  const int srow0 = (wave < 2) ? m0 : n0;
  const int sr = lane >> 2, skc = (lane & 3) * 8;

  for (int k0 = 0; k0 < CD; k0 += 32) {
#pragma unroll
    for (int i = 0; i < 8; i++) {
      const short* gp =
          gsrc + (size_t)(srow0 + i * 16 + sr) * CD + k0 + skc;
      __builtin_amdgcn_global_load_lds(
          (const __attribute__((address_space(1))) void*)gp,
          (__attribute__((address_space(3))) void*)((char*)&ldst[0][0] + i * 1024),
          16, 0, 0);
    }
    __syncthreads();
    short8 a_h[4], a_l[4], b_h[4], b_l[4];
#pragma unroll
    for (int i = 0; i < 4; i++) {
      a_h[i] = *reinterpret_cast<const short8*>(&AhS[wm + i * 16 + l15][quad * 8]);
      a_l[i] = *reinterpret_cast<const short8*>(&AlS[wm + i * 16 + l15][quad * 8]);
      b_h[i] = *reinterpret_cast<const short8*>(&BhS[wn + i * 16 + l15][quad * 8]);
      b_l[i] = *reinterpret_cast<const short8*>(&BlS[wn + i * 16 + l15][quad * 8]);
    }
#pragma unroll
    for (int im = 0; im < 4; im++)
#pragma unroll
      for (int in = 0; in < 4; in++) {
        acc[im][in] = __builtin_amdgcn_mfma_f32_16x16x32_bf16(a_h[im], b_l[in], acc[im][in], 0, 0, 0);
        acc[im][in] = __builtin_amdgcn_mfma_f32_16x16x32_bf16(a_l[im], b_h[in], acc[im][in], 0, 0, 0);
        acc[im][in] = __builtin_amdgcn_mfma_f32_16x16x32_bf16(a_h[im], b_h[in], acc[im][in], 0, 0, 0);
      }
    __syncthreads();
  }

#pragma unroll
  for (int im = 0; im < 4; im++)
#pragma unroll
    for (int in = 0; in < 4; in++)
#pragma unroll
      for (int r = 0; r < 4; r++) {
        const int mr = m0 + wm + im * 16 + quad * 4 + r;
        const int nc = n0 + wn + in * 16 + l15;
        const float val = acc[im][in][r];
        if (fp32out) {
          Cf[(size_t)mr * CD + nc] = val;
        } else {
          short sh, sl;
          split1(val, sh, sl);
          if (sel == 0) {
            O0h[(size_t)mr * CD + nc] = sh; O0l[(size_t)mr * CD + nc] = sl;
          } else if (sel == 1) {
            O1h[(size_t)mr * CD + nc] = sh; O1l[(size_t)mr * CD + nc] = sl;
          } else {  // vT[dim][seq]
            O2h[(size_t)nc * CL + mr] = sh; O2l[(size_t)nc * CL + mr] = sl;
          }
        }
      }
}

// R17 (= R16 resubmitted; R14/R15/R16 all infra-failed, never measured):
// 16-row attn16 structure measured at 346us (R3), DPP wave reductions being
// the only change. WG = 1024 thr (16 waves) x (head, 16 q-rows).
// Phase 1: 256-col tiles, wave w computes cols 16w..16w+15, causal-tail skip,
//   double-buffered Stile (one barrier/tile). Phase 2: 16 rows' Michelot in
//   parallel (one wave each), scores in VGPRs. Phase 3: P@V with wave =
//   (kgroup, dim-block), double-buffered Ptile, tail skip; LDS reduce.
__global__ __launch_bounds__(1024, 4) void attn16(
    const short* __restrict__ qh, const short* __restrict__ ql,
    const short* __restrict__ kh, const short* __restrict__ kl,
    const short* __restrict__ vhT, const short* __restrict__ vlT,
    short* __restrict__ oh, short* __restrict__ ol) {
  __shared__ float Stile[2][16][260];           // 33.3 KB
  __shared__ unsigned short Ptile[2][16][264];  // 16.5 KB
  __shared__ float Rtile[4][16][68];            // 17.4 KB partial PV
  __shared__ float invS[16];                    // total ~67.6 KB

  const int tid = threadIdx.x, lane = tid & 63, wave = tid >> 6;
  const int l15 = lane & 15, quad = lane >> 4;
  const int bx = blockIdx.x;
  const int qb = (bx & 1) ? (127 - (bx >> 1)) : (bx >> 1);  // heavy+light mix
  const int h = blockIdx.y, q0 = qb * 16, col0 = h * CHD;
  const int grow = q0 + wave;                 // this wave's global q-row
  const int ntiles = (q0 + 271) >> 8;         // 256-col tiles covering 0..q0+15
  const int rmax = q0 + 15;                   // last valid column in this block

  // Q A-frags (rows q0..q0+15): m=l15, k=kb*32+quad*8+j [m89/m91 layout]
  short8 a_h[2], a_l[2];
  {
    const size_t qbase = (size_t)(q0 + l15) * CD + col0 + quad * 8;
#pragma unroll
    for (int kb = 0; kb < 2; kb++) {
      a_h[kb] = *reinterpret_cast<const short8*>(qh + qbase + kb * 32);
      a_l[kb] = *reinterpret_cast<const short8*>(ql + qbase + kb * 32);
    }
  }

  f32x32 s;
#pragma unroll
  for (int t = 0; t < 32; t++) s[t] = NEGS;

  // ---- Phase 1: scores ----
#pragma unroll
  for (int jt = 0; jt < 8; jt++) {
    if (jt < ntiles) {                        // WG-uniform
      const int j0 = jt * 256;
      const int buf = jt & 1;
      if (j0 + 16 * wave <= rmax) {           // wave-uniform causal-tail skip
        const size_t kbase = (size_t)(j0 + 16 * wave + l15) * CD + col0 + quad * 8;
        f32x4 c = {0.f, 0.f, 0.f, 0.f};
#pragma unroll
        for (int kb = 0; kb < 2; kb++) {
          const short8 b_h = *reinterpret_cast<const short8*>(kh + kbase + kb * 32);
          const short8 b_l = *reinterpret_cast<const short8*>(kl + kbase + kb * 32);
          c = __builtin_amdgcn_mfma_f32_16x16x32_bf16(a_l[kb], b_l, c, 0, 0, 0);
          c = __builtin_amdgcn_mfma_f32_16x16x32_bf16(a_h[kb], b_l, c, 0, 0, 0);
          c = __builtin_amdgcn_mfma_f32_16x16x32_bf16(a_l[kb], b_h, c, 0, 0, 0);
          c = __builtin_amdgcn_mfma_f32_16x16x32_bf16(a_h[kb], b_h, c, 0, 0, 0);
        }
        // C layout: col(seq within tile) = 16*wave + l15, row(q) = quad*4 + r
#pragma unroll
        for (int r = 0; r < 4; r++) Stile[buf][quad * 4 + r][16 * wave + l15] = c[r];
      }
      __syncthreads();
      // Gather MY row: lane ll owns cols j0 + 64*tt + ll (conflict-free b32)
#pragma unroll
      for (int tt = 0; tt < 4; tt++) {
        if (j0 + 64 * tt <= grow) {           // wave-uniform: whole group valid?
          const int col = j0 + 64 * tt + lane;
          const float v = Stile[buf][wave][64 * tt + lane] * 0.125f;  // exact
          s[jt * 4 + tt] = (col <= grow) ? v : NEGS;
        }
      }
      // no trailing barrier: next scatter targets the other buffer
    }
  }

  // ---- Phase 2: entmax, 16 rows fully parallel (one wave each) ----
  const float inv = entmax1(s);
  if (lane == 0) invS[wave] = inv;

  // ---- Phase 3: P @ V (wave = (kgroup, dim-block)) ----
  f32x4 acc = {0.f, 0.f, 0.f, 0.f};
  const int db = wave & 3, kcg = wave >> 2;
#pragma unroll
  for (int jt = 0; jt < 8; jt++) {
    if (jt < ntiles) {
      const int j0 = jt * 256;
      const int buf = jt & 1;
      // write MY row's p for this tile (bf16; zeros where masked)
#pragma unroll
      for (int tt = 0; tt < 4; tt++)
        if (j0 + 64 * tt <= rmax)             // skip groups no chunk reads
          Ptile[buf][wave][64 * tt + lane] = bf16_bits(s[jt * 4 + tt]);
      __syncthreads();
      const size_t vrowbase =
          (size_t)(col0 + 16 * db + l15) * CL + j0;
#pragma unroll
      for (int t2 = 0; t2 < 2; t2++) {
        const int kc = 2 * kcg + t2;  // this wave's K-chunk of 32
        if (j0 + kc * 32 <= rmax) {           // wave-uniform causal-tail skip
          const short8 pa =
              *reinterpret_cast<const short8*>(&Ptile[buf][l15][kc * 32 + quad * 8]);
          const size_t vb = vrowbase + kc * 32 + quad * 8;
          const short8 vbh = *reinterpret_cast<const short8*>(vhT + vb);
          const short8 vbl = *reinterpret_cast<const short8*>(vlT + vb);
          acc = __builtin_amdgcn_mfma_f32_16x16x32_bf16(pa, vbl, acc, 0, 0, 0);
          acc = __builtin_amdgcn_mfma_f32_16x16x32_bf16(pa, vbh, acc, 0, 0, 0);
        }
      }
      // no trailing barrier: next P-write targets the other buffer
    }
  }

  // ---- Cross-wave K-group reduce + epilogue ----
#pragma unroll
  for (int r = 0; r < 4; r++) Rtile[kcg][quad * 4 + r][db * 16 + l15] = acc[r];
  __syncthreads();
  if (wave < 4) {  // wave u handles dim-block u for all 16 rows
#pragma unroll
    for (int r = 0; r < 4; r++) {
      const int row = quad * 4 + r;
      float o = (Rtile[0][row][wave * 16 + l15] + Rtile[1][row][wave * 16 + l15]) +
                (Rtile[2][row][wave * 16 + l15] + Rtile[3][row][wave * 16 + l15]);
      o *= invS[row];
      short sh, sl;
      split1(o, sh, sl);
      const size_t oidx = (size_t)(q0 + row) * CD + col0 + wave * 16 + l15;
      oh[oidx] = sh;
      ol[oidx] = sl;
    }
  }
}

extern "C" void kernel_launch(void* const* d_in, const int* in_sizes, int n_in,
                              void* d_out, int out_size, void* d_ws, size_t ws_size,
                              hipStream_t stream) {
  const float* x  = (const float*)d_in[0];
  const float* Wq = (const float*)d_in[1];
  const float* Wk = (const float*)d_in[2];
  const float* Wv = (const float*)d_in[3];
  const float* Wo = (const float*)d_in[4];
  float* out = (float*)d_out;

  // Workspace layout (56 MB total)
  char* ws = (char*)d_ws;
  short* xh  = (short*)(ws + (0ull  << 20));
  short* xl  = (short*)(ws + (4ull  << 20));
  short* wqh = (short*)(ws + (8ull  << 20));
  short* wql = (short*)(ws + (10ull << 20));
  short* wkh = (short*)(ws + (12ull << 20));
  short* wkl = (short*)(ws + (14ull << 20));
  short* wvh = (short*)(ws + (16ull << 20));
  short* wvl = (short*)(ws + (18ull << 20));
  short* woh = (short*)(ws + (20ull << 20));
  short* wol = (short*)(ws + (22ull << 20));
  short* qhp = (short*)(ws + (24ull << 20));
  short* qlp = (short*)(ws + (28ull << 20));
  short* khp = (short*)(ws + (32ull << 20));
  short* klp = (short*)(ws + (36ull << 20));
  short* vhT = (short*)(ws + (40ull << 20));
  short* vlT = (short*)(ws + (44ull << 20));
  short* ohp = (short*)(ws + (48ull << 20));
  short* olp = (short*)(ws + (52ull << 20));

  split_all<<<6144, 256, 0, stream>>>(x, Wq, Wk, Wv, Wo,
                                      xh, xl, wqh, wql, wkh, wkl,
                                      wvh, wvl, woh, wol);

  // Fused QKV: grid.x = 24, sel = x>>3 -> q/k planes row-major, vT transposed
  gemm128_split<<<dim3(24, CL / 128), 256, 0, stream>>>(
      xh, xl, wqh, wql, wkh, wkl, wvh, wvl,
      qhp, qlp, khp, klp, vhT, vlT, nullptr, 0);

  attn16<<<dim3(CL / 16, CH), 1024, 0, stream>>>(
      qhp, qlp, khp, klp, vhT, vlT, ohp, olp);

  // Wo: grid.x = 8 (sel = 0), fp32 out
  gemm128_split<<<dim3(8, CL / 128), 256, 0, stream>>>(
      ohp, olp, woh, wol, woh, wol, woh, wol,
      ohp, olp, ohp, olp, ohp, olp, out, 1);
}

// Round 10
// 486.483 us; speedup vs baseline: 1.1748x; 1.0397x over previous
//
#include <hip/hip_runtime.h>
#include <hip/hip_bf16.h>

// Problem constants (B=1)
#define CL 2048   // sequence length
#define CD 1024   // hidden
#define CH 16     // heads
#define CHD 64    // head dim
#define NEGS -1e30f

typedef __attribute__((ext_vector_type(8))) short short8;  // 8 x bf16 frag
typedef __attribute__((ext_vector_type(4))) float f32x4;
// One row of scores per WAVE: 32 regs, static indices everywhere.
typedef __attribute__((ext_vector_type(32))) float f32x32;

// DPP wave reductions (R16, measured R9: helped only ~8us -> phase 2 is
// VALU-ISSUE-bound, not shuffle-latency-bound; kept because strictly better).
template <int CTRL>
__device__ __forceinline__ float dpp_add_step(float x) {
  int v = __builtin_amdgcn_update_dpp(0, __builtin_bit_cast(int, x),
                                      CTRL, 0xf, 0xf, true);
  return x + __builtin_bit_cast(float, v);
}
template <int CTRL>
__device__ __forceinline__ float dpp_max_step(float x) {
  int v = __builtin_amdgcn_update_dpp((int)0xff800000, __builtin_bit_cast(int, x),
                                      CTRL, 0xf, 0xf, false);
  return fmaxf(x, __builtin_bit_cast(float, v));
}
__device__ __forceinline__ float wave_sum(float x) {
  x = dpp_add_step<0x111>(x);  // row_shr:1
  x = dpp_add_step<0x112>(x);  // row_shr:2
  x = dpp_add_step<0x114>(x);  // row_shr:4
  x = dpp_add_step<0x118>(x);  // row_shr:8
  x = dpp_add_step<0x142>(x);  // row_bcast:15
  x = dpp_add_step<0x143>(x);  // row_bcast:31
  return __builtin_bit_cast(float,
      __builtin_amdgcn_readlane(__builtin_bit_cast(int, x), 63));
}
__device__ __forceinline__ float wave_max(float x) {
  x = dpp_max_step<0x111>(x);
  x = dpp_max_step<0x112>(x);
  x = dpp_max_step<0x114>(x);
  x = dpp_max_step<0x118>(x);
  x = dpp_max_step<0x142>(x);
  x = dpp_max_step<0x143>(x);
  return __builtin_bit_cast(float,
      __builtin_amdgcn_readlane(__builtin_bit_cast(int, x), 63));
}

__device__ __forceinline__ void split1(float v, short& h, short& l) {
  __hip_bfloat16 bh = __float2bfloat16(v);
  __hip_bfloat16 bl = __float2bfloat16(v - __bfloat162float(bh));
  h = __builtin_bit_cast(short, bh);
  l = __builtin_bit_cast(short, bl);
}
__device__ __forceinline__ unsigned short bf16_bits(float v) {
  __hip_bfloat16 b = __float2bfloat16(v);
  return (unsigned short)__builtin_bit_cast(short, b);
}

// ---- depth-5 tree helpers over f32x32 (one-shot; unguarded on purpose:
// relu MUST zero the causally-masked elems for the Ptile write) ----
__device__ __forceinline__ float tree_sum_valid(const f32x32& s) {
  float t[8];
#pragma unroll
  for (int i = 0; i < 8; i++) {
    const float a = s[i]      > -1e29f ? s[i]      : 0.f;
    const float b = s[i + 8]  > -1e29f ? s[i + 8]  : 0.f;
    const float c = s[i + 16] > -1e29f ? s[i + 16] : 0.f;
    const float d = s[i + 24] > -1e29f ? s[i + 24] : 0.f;
    t[i] = (a + b) + (c + d);
  }
#pragma unroll
  for (int i = 0; i < 4; i++) t[i] += t[i + 4];
  t[0] += t[2]; t[1] += t[3];
  return t[0] + t[1];
}
__device__ __forceinline__ float tree_max(const f32x32& s) {
  float t[8];
#pragma unroll
  for (int i = 0; i < 8; i++)
    t[i] = fmaxf(fmaxf(s[i], s[i + 8]), fmaxf(s[i + 16], s[i + 24]));
#pragma unroll
  for (int i = 0; i < 4; i++) t[i] = fmaxf(t[i], t[i + 4]);
  return fmaxf(fmaxf(t[0], t[2]), fmaxf(t[1], t[3]));
}
__device__ __forceinline__ float relu_store_sum(f32x32& s, float ts_) {
  float t[8];
#pragma unroll
  for (int i = 0; i < 8; i++) {
    float a = s[i] - ts_;      a = a > 0.f ? a : 0.f;
    float b = s[i + 8] - ts_;  b = b > 0.f ? b : 0.f;
    float c = s[i + 16] - ts_; c = c > 0.f ? c : 0.f;
    float d = s[i + 24] - ts_; d = d > 0.f ? d : 0.f;
    s[i] = a; s[i + 8] = b; s[i + 16] = c; s[i + 24] = d;
    t[i] = (a + b) + (c + d);
  }
#pragma unroll
  for (int i = 0; i < 4; i++) t[i] += t[i + 4];
  t[0] += t[2]; t[1] += t[3];
  return t[0] + t[1];
}

// R18 Michelot: per-iteration hot loop rebuilt for VALU-issue economy
// (R9 post-mortem: DPP gave -8us only; phase 2 is issue-bound at 4 waves/SIMD).
// (a) count via __popcll(__ballot(a>tau)): wave-wide int lands in SGPR via
//     s_bcnt1 on the SCALAR pipe (parallel to VALU); kills 32 cndmask +
//     32 add + one 6-step DPP reduction per iteration; v_cmp is shared
//     with the sum's cndmask (CSE). Count semantics exact (small ints).
// (b) wave-uniform causal slot skip: 256-col groups with jt*256 > grow are
//     all NEGS (never > tau since tau >= max-1) -> s_cbranch around the
//     whole group; indices stay compile-time (no scratch). Avg ~44% of
//     element work skipped (avg row has ~4.5/8 live groups).
// Michelot tau is monotone non-decreasing; fixpoint count == reference's
// sort-based k_support. Reference quirk kept: ts = (FULL masked sum-1)/cnt.
// Overwrites s with unnormalized p; returns 1/(psum+1e-10).
__device__ __forceinline__ float entmax1(f32x32& s, int grow) {
  const float ss = wave_sum(tree_sum_valid(s));
  const float m = wave_max(tree_max(s));
  float tau = m - 1.000001f;
  int cnt = 0;
  for (int it = 0; it < 64; it++) {
    float sum = 0.f;
    int c = 0;
#pragma unroll
    for (int jt = 0; jt < 8; jt++) {
      if (jt * 256 <= grow) {            // wave-uniform causal guard
        float p0 = 0.f;
#pragma unroll
        for (int tt = 0; tt < 4; tt++) {
          const float a = s[jt * 4 + tt];
          const bool pr = a > tau;
          p0 += pr ? a : 0.f;
          c += (int)__popcll(__ballot(pr));
        }
        sum += p0;
      }
    }
    const float cs = wave_sum(sum);
    if (c == cnt) break;                 // wave-uniform (SGPR int)
    cnt = c;
    tau = (cs - 1.f) / (float)c;
  }
  const float ts = (ss - 1.f) / (float)cnt;
  return 1.f / (wave_sum(relu_store_sum(s, ts)) + 1e-10f);
}

// One fused split kernel: fp32 -> bf16 hi/lo planes for x and 4 weights.
__global__ __launch_bounds__(256) void split_all(
    const float* __restrict__ x,  const float* __restrict__ wq,
    const float* __restrict__ wk, const float* __restrict__ wv,
    const float* __restrict__ wo,
    short* __restrict__ xh,  short* __restrict__ xl,
    short* __restrict__ wqh, short* __restrict__ wql,
    short* __restrict__ wkh, short* __restrict__ wkl,
    short* __restrict__ wvh, short* __restrict__ wvl,
    short* __restrict__ woh, short* __restrict__ wol) {
  const int b = blockIdx.x;
  const float* src; short *dh, *dl; int i0;
  if      (b < 2048) { src = x;  dh = xh;  dl = xl;  i0 = b; }
  else if (b < 3072) { src = wq; dh = wqh; dl = wql; i0 = b - 2048; }
  else if (b < 4096) { src = wk; dh = wkh; dl = wkl; i0 = b - 3072; }
  else if (b < 5120) { src = wv; dh = wvh; dl = wvl; i0 = b - 4096; }
  else               { src = wo; dh = woh; dl = wol; i0 = b - 5120; }
  const int i = i0 * 256 + threadIdx.x;
  const float4 v = reinterpret_cast<const float4*>(src)[i];
  const float vv[4] = {v.x, v.y, v.z, v.w};
  short hh[4], ll[4];
#pragma unroll
  for (int e = 0; e < 4; e++) split1(vv[e], hh[e], ll[e]);
  reinterpret_cast<short4*>(dh)[i] = make_short4(hh[0], hh[1], hh[2], hh[3]);
  reinterpret_cast<short4*>(dl)[i] = make_short4(ll[0], ll[1], ll[2], ll[3]);
}

// C[2048,1024] = (Ah+Al) * (B?h+B?l)^T via 3-term split-bf16 MFMA.
// 128x128 tile/WG, LDS-staged BK=32, global_load_lds width=16 staging
// (lane-linear dest: byte off = i*1024 + lane*16). Epilogue: fp32out -> Cf;
// else bf16 hi/lo planes (sel 2 = vT transposed [dim][seq]).
__global__ __launch_bounds__(256, 2) void gemm128_split(
    const short* __restrict__ Ah, const short* __restrict__ Al,
    const short* __restrict__ B0h, const short* __restrict__ B0l,
    const short* __restrict__ B1h, const short* __restrict__ B1l,
    const short* __restrict__ B2h, const short* __restrict__ B2l,
    short* __restrict__ O0h, short* __restrict__ O0l,
    short* __restrict__ O1h, short* __restrict__ O1l,
    short* __restrict__ O2h, short* __restrict__ O2l,
    float* __restrict__ Cf, int fp32out) {
  __shared__ short AhS[128][32], AlS[128][32], BhS[128][32], BlS[128][32];
  const int tid = threadIdx.x, lane = tid & 63, wave = tid >> 6;
  const int l15 = lane & 15, quad = lane >> 4;
  const int sel = blockIdx.x >> 3, nb = blockIdx.x & 7;
  const short* Bh = sel == 0 ? B0h : (sel == 1 ? B1h : B2h);
  const short* Bl = sel == 0 ? B0l : (sel == 1 ? B1l : B2l);
  const int m0 = blockIdx.y * 128, n0 = nb * 128;
  const int wm = (wave >> 1) * 64, wn = (wave & 1) * 64;

  f32x4 acc[4][4];
#pragma unroll
  for (int i = 0; i < 4; i++)
#pragma unroll
    for (int j = 0; j < 4; j++) acc[i][j] = {0.f, 0.f, 0.f, 0.f};

  const short* gsrc = wave == 0 ? Ah : wave == 1 ? Al : wave == 2 ? Bh : Bl;
  short(*ldst)[32] = wave == 0 ? AhS : wave == 1 ? AlS : wave == 2 ? BhS : BlS;
  const int srow0 = (wave < 2) ? m0 : n0;
  const int sr = lane >> 2, skc = (lane & 3) * 8;

  for (int k0 = 0; k0 < CD; k0 += 32) {
#pragma unroll
    for (int i = 0; i < 8; i++) {
      const short* gp =
          gsrc + (size_t)(srow0 + i * 16 + sr) * CD + k0 + skc;
      __builtin_amdgcn_global_load_lds(
          (const __attribute__((address_space(1))) void*)gp,
          (__attribute__((address_space(3))) void*)((char*)&ldst[0][0] + i * 1024),
          16, 0, 0);
    }
    __syncthreads();
    short8 a_h[4], a_l[4], b_h[4], b_l[4];
#pragma unroll
    for (int i = 0; i < 4; i++) {
      a_h[i] = *reinterpret_cast<const short8*>(&AhS[wm + i * 16 + l15][quad * 8]);
      a_l[i] = *reinterpret_cast<const short8*>(&AlS[wm + i * 16 + l15][quad * 8]);
      b_h[i] = *reinterpret_cast<const short8*>(&BhS[wn + i * 16 + l15][quad * 8]);
      b_l[i] = *reinterpret_cast<const short8*>(&BlS[wn + i * 16 + l15][quad * 8]);
    }
#pragma unroll
    for (int im = 0; im < 4; im++)
#pragma unroll
      for (int in = 0; in < 4; in++) {
        acc[im][in] = __builtin_amdgcn_mfma_f32_16x16x32_bf16(a_h[im], b_l[in], acc[im][in], 0, 0, 0);
        acc[im][in] = __builtin_amdgcn_mfma_f32_16x16x32_bf16(a_l[im], b_h[in], acc[im][in], 0, 0, 0);
        acc[im][in] = __builtin_amdgcn_mfma_f32_16x16x32_bf16(a_h[im], b_h[in], acc[im][in], 0, 0, 0);
      }
    __syncthreads();
  }

#pragma unroll
  for (int im = 0; im < 4; im++)
#pragma unroll
    for (int in = 0; in < 4; in++)
#pragma unroll
      for (int r = 0; r < 4; r++) {
        const int mr = m0 + wm + im * 16 + quad * 4 + r;
        const int nc = n0 + wn + in * 16 + l15;
        const float val = acc[im][in][r];
        if (fp32out) {
          Cf[(size_t)mr * CD + nc] = val;
        } else {
          short sh, sl;
          split1(val, sh, sl);
          if (sel == 0) {
            O0h[(size_t)mr * CD + nc] = sh; O0l[(size_t)mr * CD + nc] = sl;
          } else if (sel == 1) {
            O1h[(size_t)mr * CD + nc] = sh; O1l[(size_t)mr * CD + nc] = sl;
          } else {  // vT[dim][seq]
            O2h[(size_t)nc * CL + mr] = sh; O2l[(size_t)nc * CL + mr] = sl;
          }
        }
      }
}

// R18: 16-row attn16 (R9-measured structure at 337.8us) with the new
// ballot+guard Michelot. WG = 1024 thr (16 waves) x (head, 16 q-rows).
// Phase 1: 256-col tiles, wave w computes cols 16w..16w+15, causal-tail skip,
//   double-buffered Stile (one barrier/tile). Phase 2: 16 rows' Michelot in
//   parallel (one wave each), scores in VGPRs. Phase 3: P@V with wave =
//   (kgroup, dim-block), double-buffered Ptile, tail skip; LDS reduce.
__global__ __launch_bounds__(1024, 4) void attn16(
    const short* __restrict__ qh, const short* __restrict__ ql,
    const short* __restrict__ kh, const short* __restrict__ kl,
    const short* __restrict__ vhT, const short* __restrict__ vlT,
    short* __restrict__ oh, short* __restrict__ ol) {
  __shared__ float Stile[2][16][260];           // 33.3 KB
  __shared__ unsigned short Ptile[2][16][264];  // 16.5 KB
  __shared__ float Rtile[4][16][68];            // 17.4 KB partial PV
  __shared__ float invS[16];                    // total ~67.6 KB

  const int tid = threadIdx.x, lane = tid & 63, wave = tid >> 6;
  const int l15 = lane & 15, quad = lane >> 4;
  const int bx = blockIdx.x;
  const int qb = (bx & 1) ? (127 - (bx >> 1)) : (bx >> 1);  // heavy+light mix
  const int h = blockIdx.y, q0 = qb * 16, col0 = h * CHD;
  const int grow = q0 + wave;                 // this wave's global q-row
  const int ntiles = (q0 + 271) >> 8;         // 256-col tiles covering 0..q0+15
  const int rmax = q0 + 15;                   // last valid column in this block

  // Q A-frags (rows q0..q0+15): m=l15, k=kb*32+quad*8+j [m89/m91 layout]
  short8 a_h[2], a_l[2];
  {
    const size_t qbase = (size_t)(q0 + l15) * CD + col0 + quad * 8;
#pragma unroll
    for (int kb = 0; kb < 2; kb++) {
      a_h[kb] = *reinterpret_cast<const short8*>(qh + qbase + kb * 32);
      a_l[kb] = *reinterpret_cast<const short8*>(ql + qbase + kb * 32);
    }
  }

  f32x32 s;
#pragma unroll
  for (int t = 0; t < 32; t++) s[t] = NEGS;

  // ---- Phase 1: scores ----
#pragma unroll
  for (int jt = 0; jt < 8; jt++) {
    if (jt < ntiles) {                        // WG-uniform
      const int j0 = jt * 256;
      const int buf = jt & 1;
      if (j0 + 16 * wave <= rmax) {           // wave-uniform causal-tail skip
        const size_t kbase = (size_t)(j0 + 16 * wave + l15) * CD + col0 + quad * 8;
        f32x4 c = {0.f, 0.f, 0.f, 0.f};
#pragma unroll
        for (int kb = 0; kb < 2; kb++) {
          const short8 b_h = *reinterpret_cast<const short8*>(kh + kbase + kb * 32);
          const short8 b_l = *reinterpret_cast<const short8*>(kl + kbase + kb * 32);
          c = __builtin_amdgcn_mfma_f32_16x16x32_bf16(a_l[kb], b_l, c, 0, 0, 0);
          c = __builtin_amdgcn_mfma_f32_16x16x32_bf16(a_h[kb], b_l, c, 0, 0, 0);
          c = __builtin_amdgcn_mfma_f32_16x16x32_bf16(a_l[kb], b_h, c, 0, 0, 0);
          c = __builtin_amdgcn_mfma_f32_16x16x32_bf16(a_h[kb], b_h, c, 0, 0, 0);
        }
        // C layout: col(seq within tile) = 16*wave + l15, row(q) = quad*4 + r
#pragma unroll
        for (int r = 0; r < 4; r++) Stile[buf][quad * 4 + r][16 * wave + l15] = c[r];
      }
      __syncthreads();
      // Gather MY row: lane ll owns cols j0 + 64*tt + ll (conflict-free b32)
#pragma unroll
      for (int tt = 0; tt < 4; tt++) {
        if (j0 + 64 * tt <= grow) {           // wave-uniform: whole group valid?
          const int col = j0 + 64 * tt + lane;
          const float v = Stile[buf][wave][64 * tt + lane] * 0.125f;  // exact
          s[jt * 4 + tt] = (col <= grow) ? v : NEGS;
        }
      }
      // no trailing barrier: next scatter targets the other buffer
    }
  }

  // ---- Phase 2: entmax, 16 rows fully parallel (one wave each) ----
  const float inv = entmax1(s, grow);
  if (lane == 0) invS[wave] = inv;

  // ---- Phase 3: P @ V (wave = (kgroup, dim-block)) ----
  f32x4 acc = {0.f, 0.f, 0.f, 0.f};
  const int db = wave & 3, kcg = wave >> 2;
#pragma unroll
  for (int jt = 0; jt < 8; jt++) {
    if (jt < ntiles) {
      const int j0 = jt * 256;
      const int buf = jt & 1;
      // write MY row's p for this tile (bf16; zeros where masked)
#pragma unroll
      for (int tt = 0; tt < 4; tt++)
        if (j0 + 64 * tt <= rmax)             // skip groups no chunk reads
          Ptile[buf][wave][64 * tt + lane] = bf16_bits(s[jt * 4 + tt]);
      __syncthreads();
      const size_t vrowbase =
          (size_t)(col0 + 16 * db + l15) * CL + j0;
#pragma unroll
      for (int t2 = 0; t2 < 2; t2++) {
        const int kc = 2 * kcg + t2;  // this wave's K-chunk of 32
        if (j0 + kc * 32 <= rmax) {           // wave-uniform causal-tail skip
          const short8 pa =
              *reinterpret_cast<const short8*>(&Ptile[buf][l15][kc * 32 + quad * 8]);
          const size_t vb = vrowbase + kc * 32 + quad * 8;
          const short8 vbh = *reinterpret_cast<const short8*>(vhT + vb);
          const short8 vbl = *reinterpret_cast<const short8*>(vlT + vb);
          acc = __builtin_amdgcn_mfma_f32_16x16x32_bf16(pa, vbl, acc, 0, 0, 0);
          acc = __builtin_amdgcn_mfma_f32_16x16x32_bf16(pa, vbh, acc, 0, 0, 0);
        }
      }
      // no trailing barrier: next P-write targets the other buffer
    }
  }

  // ---- Cross-wave K-group reduce + epilogue ----
#pragma unroll
  for (int r = 0; r < 4; r++) Rtile[kcg][quad * 4 + r][db * 16 + l15] = acc[r];
  __syncthreads();
  if (wave < 4) {  // wave u handles dim-block u for all 16 rows
#pragma unroll
    for (int r = 0; r < 4; r++) {
      const int row = quad * 4 + r;
      float o = (Rtile[0][row][wave * 16 + l15] + Rtile[1][row][wave * 16 + l15]) +
                (Rtile[2][row][wave * 16 + l15] + Rtile[3][row][wave * 16 + l15]);
      o *= invS[row];
      short sh, sl;
      split1(o, sh, sl);
      const size_t oidx = (size_t)(q0 + row) * CD + col0 + wave * 16 + l15;
      oh[oidx] = sh;
      ol[oidx] = sl;
    }
  }
}

extern "C" void kernel_launch(void* const* d_in, const int* in_sizes, int n_in,
                              void* d_out, int out_size, void* d_ws, size_t ws_size,
                              hipStream_t stream) {
  const float* x  = (const float*)d_in[0];
  const float* Wq = (const float*)d_in[1];
  const float* Wk = (const float*)d_in[2];
  const float* Wv = (const float*)d_in[3];
  const float* Wo = (const float*)d_in[4];
  float* out = (float*)d_out;

  // Workspace layout (56 MB total)
  char* ws = (char*)d_ws;
  short* xh  = (short*)(ws + (0ull  << 20));
  short* xl  = (short*)(ws + (4ull  << 20));
  short* wqh = (short*)(ws + (8ull  << 20));
  short* wql = (short*)(ws + (10ull << 20));
  short* wkh = (short*)(ws + (12ull << 20));
  short* wkl = (short*)(ws + (14ull << 20));
  short* wvh = (short*)(ws + (16ull << 20));
  short* wvl = (short*)(ws + (18ull << 20));
  short* woh = (short*)(ws + (20ull << 20));
  short* wol = (short*)(ws + (22ull << 20));
  short* qhp = (short*)(ws + (24ull << 20));
  short* qlp = (short*)(ws + (28ull << 20));
  short* khp = (short*)(ws + (32ull << 20));
  short* klp = (short*)(ws + (36ull << 20));
  short* vhT = (short*)(ws + (40ull << 20));
  short* vlT = (short*)(ws + (44ull << 20));
  short* ohp = (short*)(ws + (48ull << 20));
  short* olp = (short*)(ws + (52ull << 20));

  split_all<<<6144, 256, 0, stream>>>(x, Wq, Wk, Wv, Wo,
                                      xh, xl, wqh, wql, wkh, wkl,
                                      wvh, wvl, woh, wol);

  // Fused QKV: grid.x = 24, sel = x>>3 -> q/k planes row-major, vT transposed
  gemm128_split<<<dim3(24, CL / 128), 256, 0, stream>>>(
      xh, xl, wqh, wql, wkh, wkl, wvh, wvl,
      qhp, qlp, khp, klp, vhT, vlT, nullptr, 0);

  attn16<<<dim3(CL / 16, CH), 1024, 0, stream>>>(
      qhp, qlp, khp, klp, vhT, vlT, ohp, olp);

  // Wo: grid.x = 8 (sel = 0), fp32 out
  gemm128_split<<<dim3(8, CL / 128), 256, 0, stream>>>(
      ohp, olp, woh, wol, woh, wol, woh, wol,
      ohp, olp, ohp, olp, ohp, olp, out, 1);
}

// Round 12
// 406.535 us; speedup vs baseline: 1.4058x; 1.1967x over previous
//
#include <hip/hip_runtime.h>
#include <hip/hip_bf16.h>

// Problem constants (B=1)
#define CL 2048   // sequence length
#define CD 1024   // hidden
#define CH 16     // heads
#define CHD 64    // head dim
#define NEGS -1e30f

typedef __attribute__((ext_vector_type(8))) short short8;  // 8 x bf16 frag
typedef __attribute__((ext_vector_type(4))) float f32x4;
// One row of scores: 32 regs, static indices everywhere.
typedef __attribute__((ext_vector_type(32))) float f32x32;

// DPP wave reductions (R16; measured R9 ~-8us, kept: strictly better).
template <int CTRL>
__device__ __forceinline__ float dpp_add_step(float x) {
  int v = __builtin_amdgcn_update_dpp(0, __builtin_bit_cast(int, x),
                                      CTRL, 0xf, 0xf, true);
  return x + __builtin_bit_cast(float, v);
}
template <int CTRL>
__device__ __forceinline__ float dpp_max_step(float x) {
  int v = __builtin_amdgcn_update_dpp((int)0xff800000, __builtin_bit_cast(int, x),
                                      CTRL, 0xf, 0xf, false);
  return fmaxf(x, __builtin_bit_cast(float, v));
}
__device__ __forceinline__ float wave_sum(float x) {
  x = dpp_add_step<0x111>(x);  // row_shr:1
  x = dpp_add_step<0x112>(x);  // row_shr:2
  x = dpp_add_step<0x114>(x);  // row_shr:4
  x = dpp_add_step<0x118>(x);  // row_shr:8
  x = dpp_add_step<0x142>(x);  // row_bcast:15
  x = dpp_add_step<0x143>(x);  // row_bcast:31
  return __builtin_bit_cast(float,
      __builtin_amdgcn_readlane(__builtin_bit_cast(int, x), 63));
}
__device__ __forceinline__ float wave_max(float x) {
  x = dpp_max_step<0x111>(x);
  x = dpp_max_step<0x112>(x);
  x = dpp_max_step<0x114>(x);
  x = dpp_max_step<0x118>(x);
  x = dpp_max_step<0x142>(x);
  x = dpp_max_step<0x143>(x);
  return __builtin_bit_cast(float,
      __builtin_amdgcn_readlane(__builtin_bit_cast(int, x), 63));
}

__device__ __forceinline__ void split1(float v, short& h, short& l) {
  __hip_bfloat16 bh = __float2bfloat16(v);
  __hip_bfloat16 bl = __float2bfloat16(v - __bfloat162float(bh));
  h = __builtin_bit_cast(short, bh);
  l = __builtin_bit_cast(short, bl);
}
__device__ __forceinline__ unsigned short bf16_bits(float v) {
  __hip_bfloat16 b = __float2bfloat16(v);
  return (unsigned short)__builtin_bit_cast(short, b);
}

// ---- depth-5 tree helpers over f32x32 (one-shot; unguarded on purpose:
// relu MUST zero the causally-masked elems for the Ptile write) ----
__device__ __forceinline__ float tree_sum_valid(const f32x32& s) {
  float t[8];
#pragma unroll
  for (int i = 0; i < 8; i++) {
    const float a = s[i]      > -1e29f ? s[i]      : 0.f;
    const float b = s[i + 8]  > -1e29f ? s[i + 8]  : 0.f;
    const float c = s[i + 16] > -1e29f ? s[i + 16] : 0.f;
    const float d = s[i + 24] > -1e29f ? s[i + 24] : 0.f;
    t[i] = (a + b) + (c + d);
  }
#pragma unroll
  for (int i = 0; i < 4; i++) t[i] += t[i + 4];
  t[0] += t[2]; t[1] += t[3];
  return t[0] + t[1];
}
__device__ __forceinline__ float tree_max(const f32x32& s) {
  float t[8];
#pragma unroll
  for (int i = 0; i < 8; i++)
    t[i] = fmaxf(fmaxf(s[i], s[i + 8]), fmaxf(s[i + 16], s[i + 24]));
#pragma unroll
  for (int i = 0; i < 4; i++) t[i] = fmaxf(t[i], t[i + 4]);
  return fmaxf(fmaxf(t[0], t[2]), fmaxf(t[1], t[3]));
}
__device__ __forceinline__ float relu_store_sum(f32x32& s, float ts_) {
  float t[8];
#pragma unroll
  for (int i = 0; i < 8; i++) {
    float a = s[i] - ts_;      a = a > 0.f ? a : 0.f;
    float b = s[i + 8] - ts_;  b = b > 0.f ? b : 0.f;
    float c = s[i + 16] - ts_; c = c > 0.f ? c : 0.f;
    float d = s[i + 24] - ts_; d = d > 0.f ? d : 0.f;
    s[i] = a; s[i + 8] = b; s[i + 16] = c; s[i + 24] = d;
    t[i] = (a + b) + (c + d);
  }
#pragma unroll
  for (int i = 0; i < 4; i++) t[i] += t[i + 4];
  t[0] += t[2]; t[1] += t[3];
  return t[0] + t[1];
}

// R19/R20: fused 2-row Michelot (rows g0, g1 per wave). R10 post-mortem:
// VALU-issue cut gave only -20us -> phase 2 is serial-CHAIN-bound; two
// independent rows give 2-way ILP on the chain and trip count max(it0,it1)
// instead of it0+it1. Straight-line per iteration (causal guards are
// it-invariant wave-uniform branches); tau/cnt updates gated per row.
// A row that stabilizes keeps c==cnt (tau frozen -> same candidate set), so
// freezing is stable; loop exits when both stable. Semantics per row identical
// to R10's entmax1 (ballot count; reference quirk ts=(full sum-1)/cnt kept).
__device__ __forceinline__ void entmax_pair(f32x32& s0, f32x32& s1,
                                            int g0, int g1,
                                            float& inv0, float& inv1) {
  const float ss0 = wave_sum(tree_sum_valid(s0));
  const float m0  = wave_max(tree_max(s0));
  const float ss1 = wave_sum(tree_sum_valid(s1));
  const float m1  = wave_max(tree_max(s1));
  float tau0 = m0 - 1.000001f, tau1 = m1 - 1.000001f;
  int cnt0 = 0, cnt1 = 0;
  for (int it = 0; it < 64; it++) {
    float sum0 = 0.f, sum1 = 0.f;
    int c0 = 0, c1 = 0;
#pragma unroll
    for (int jt = 0; jt < 8; jt++) {
      if (jt * 256 <= g0) {             // wave-uniform causal guard (row 0)
#pragma unroll
        for (int tt = 0; tt < 4; tt++) {
          const float a = s0[jt * 4 + tt];
          const bool pr = a > tau0;
          sum0 += pr ? a : 0.f;
          c0 += (int)__popcll(__ballot(pr));
        }
      }
      if (jt * 256 <= g1) {             // wave-uniform causal guard (row 1)
#pragma unroll
        for (int tt = 0; tt < 4; tt++) {
          const float a = s1[jt * 4 + tt];
          const bool pr = a > tau1;
          sum1 += pr ? a : 0.f;
          c1 += (int)__popcll(__ballot(pr));
        }
      }
    }
    const float cs0 = wave_sum(sum0);   // two independent DPP chains:
    const float cs1 = wave_sum(sum1);   // compiler interleaves (ILP)
    const bool st0 = (c0 == cnt0), st1 = (c1 == cnt1);
    if (st0 && st1) break;
    if (!st0) { cnt0 = c0; tau0 = (cs0 - 1.f) / (float)c0; }
    if (!st1) { cnt1 = c1; tau1 = (cs1 - 1.f) / (float)c1; }
  }
  const float ts0 = (ss0 - 1.f) / (float)cnt0;
  const float ts1 = (ss1 - 1.f) / (float)cnt1;
  inv0 = 1.f / (wave_sum(relu_store_sum(s0, ts0)) + 1e-10f);
  inv1 = 1.f / (wave_sum(relu_store_sum(s1, ts1)) + 1e-10f);
}

// One fused split kernel: fp32 -> bf16 hi/lo planes for x and 4 weights.
__global__ __launch_bounds__(256) void split_all(
    const float* __restrict__ x,  const float* __restrict__ wq,
    const float* __restrict__ wk, const float* __restrict__ wv,
    const float* __restrict__ wo,
    short* __restrict__ xh,  short* __restrict__ xl,
    short* __restrict__ wqh, short* __restrict__ wql,
    short* __restrict__ wkh, short* __restrict__ wkl,
    short* __restrict__ wvh, short* __restrict__ wvl,
    short* __restrict__ woh, short* __restrict__ wol) {
  const int b = blockIdx.x;
  const float* src; short *dh, *dl; int i0;
  if      (b < 2048) { src = x;  dh = xh;  dl = xl;  i0 = b; }
  else if (b < 3072) { src = wq; dh = wqh; dl = wql; i0 = b - 2048; }
  else if (b < 4096) { src = wk; dh = wkh; dl = wkl; i0 = b - 3072; }
  else if (b < 5120) { src = wv; dh = wvh; dl = wvl; i0 = b - 4096; }
  else               { src = wo; dh = woh; dl = wol; i0 = b - 5120; }
  const int i = i0 * 256 + threadIdx.x;
  const float4 v = reinterpret_cast<const float4*>(src)[i];
  const float vv[4] = {v.x, v.y, v.z, v.w};
  short hh[4], ll[4];
#pragma unroll
  for (int e = 0; e < 4; e++) split1(vv[e], hh[e], ll[e]);
  reinterpret_cast<short4*>(dh)[i] = make_short4(hh[0], hh[1], hh[2], hh[3]);
  reinterpret_cast<short4*>(dl)[i] = make_short4(ll[0], ll[1], ll[2], ll[3]);
}

// C[2048,1024] = (Ah+Al) * (B?h+B?l)^T via 3-term split-bf16 MFMA.
// 128x128 tile/WG, LDS-staged BK=32, global_load_lds width=16 staging
// (lane-linear dest: byte off = i*1024 + lane*16). Epilogue: fp32out -> Cf;
// else bf16 hi/lo planes (sel 2 = vT transposed [dim][seq]).
__global__ __launch_bounds__(256, 2) void gemm128_split(
    const short* __restrict__ Ah, const short* __restrict__ Al,
    const short* __restrict__ B0h, const short* __restrict__ B0l,
    const short* __restrict__ B1h, const short* __restrict__ B1l,
    const short* __restrict__ B2h, const short* __restrict__ B2l,
    short* __restrict__ O0h, short* __restrict__ O0l,
    short* __restrict__ O1h, short* __restrict__ O1l,
    short* __restrict__ O2h, short* __restrict__ O2l,
    float* __restrict__ Cf, int fp32out) {
  __shared__ short AhS[128][32], AlS[128][32], BhS[128][32], BlS[128][32];
  const int tid = threadIdx.x, lane = tid & 63, wave = tid >> 6;
  const int l15 = lane & 15, quad = lane >> 4;
  const int sel = blockIdx.x >> 3, nb = blockIdx.x & 7;
  const short* Bh = sel == 0 ? B0h : (sel == 1 ? B1h : B2h);
  const short* Bl = sel == 0 ? B0l : (sel == 1 ? B1l : B2l);
  const int m0 = blockIdx.y * 128, n0 = nb * 128;
  const int wm = (wave >> 1) * 64, wn = (wave & 1) * 64;

  f32x4 acc[4][4];
#pragma unroll
  for (int i = 0; i < 4; i++)
#pragma unroll
    for (int j = 0; j < 4; j++) acc[i][j] = {0.f, 0.f, 0.f, 0.f};

  const short* gsrc = wave == 0 ? Ah : wave == 1 ? Al : wave == 2 ? Bh : Bl;
  short(*ldst)[32] = wave == 0 ? AhS : wave == 1 ? AlS : wave == 2 ? BhS : BlS;
  const int srow0 = (wave < 2) ? m0 : n0;
  const int sr = lane >> 2, skc = (lane & 3) * 8;

  for (int k0 = 0; k0 < CD; k0 += 32) {
#pragma unroll
    for (int i = 0; i < 8; i++) {
      const short* gp =
          gsrc + (size_t)(srow0 + i * 16 + sr) * CD + k0 + skc;
      __builtin_amdgcn_global_load_lds(
          (const __attribute__((address_space(1))) void*)gp,
          (__attribute__((address_space(3))) void*)((char*)&ldst[0][0] + i * 1024),
          16, 0, 0);
    }
    __syncthreads();
    short8 a_h[4], a_l[4], b_h[4], b_l[4];
#pragma unroll
    for (int i = 0; i < 4; i++) {
      a_h[i] = *reinterpret_cast<const short8*>(&AhS[wm + i * 16 + l15][quad * 8]);
      a_l[i] = *reinterpret_cast<const short8*>(&AlS[wm + i * 16 + l15][quad * 8]);
      b_h[i] = *reinterpret_cast<const short8*>(&BhS[wn + i * 16 + l15][quad * 8]);
      b_l[i] = *reinterpret_cast<const short8*>(&BlS[wn + i * 16 + l15][quad * 8]);
    }
#pragma unroll
    for (int im = 0; im < 4; im++)
#pragma unroll
      for (int in = 0; in < 4; in++) {
        acc[im][in] = __builtin_amdgcn_mfma_f32_16x16x32_bf16(a_h[im], b_l[in], acc[im][in], 0, 0, 0);
        acc[im][in] = __builtin_amdgcn_mfma_f32_16x16x32_bf16(a_l[im], b_h[in], acc[im][in], 0, 0, 0);
        acc[im][in] = __builtin_amdgcn_mfma_f32_16x16x32_bf16(a_h[im], b_h[in], acc[im][in], 0, 0, 0);
      }
    __syncthreads();
  }

#pragma unroll
  for (int im = 0; im < 4; im++)
#pragma unroll
    for (int in = 0; in < 4; in++)
#pragma unroll
      for (int r = 0; r < 4; r++) {
        const int mr = m0 + wm + im * 16 + quad * 4 + r;
        const int nc = n0 + wn + in * 16 + l15;
        const float val = acc[im][in][r];
        if (fp32out) {
          Cf[(size_t)mr * CD + nc] = val;
        } else {
          short sh, sl;
          split1(val, sh, sl);
          if (sel == 0) {
            O0h[(size_t)mr * CD + nc] = sh; O0l[(size_t)mr * CD + nc] = sl;
          } else if (sel == 1) {
            O1h[(size_t)mr * CD + nc] = sh; O1l[(size_t)mr * CD + nc] = sl;
          } else {  // vT[dim][seq]
            O2h[(size_t)nc * CL + mr] = sh; O2l[(size_t)nc * CL + mr] = sl;
          }
        }
      }
}

// R20 (= R19 resubmitted; R19 bench was a container-level infra failure):
// attn32 — 32 q-rows per WG (2 rows per wave), grid (64,16).
// Inverse of R5's measured loss (8-row WG cost +67us from lost amortization):
// K/V loads, barriers, prologues amortize over 2x rows; Michelot runs two
// independent chains per wave (ILP on the serial chain R10 proved dominant);
// blocks 2048->1024. LDS 132KB (1 block/CU, as before). Registers ~120/128.
// Wave w owns rows q0+w (s0) and q0+16+w (s1). 32-row blocks tile CL exactly
// (no Q-overrun). All guards keep the attn16 proven forms with rmax=q0+31.
__global__ __launch_bounds__(1024, 4) void attn32(
    const short* __restrict__ qh, const short* __restrict__ ql,
    const short* __restrict__ kh, const short* __restrict__ kl,
    const short* __restrict__ vhT, const short* __restrict__ vlT,
    short* __restrict__ oh, short* __restrict__ ol) {
  __shared__ float Stile[2][32][260];           // 66.6 KB
  __shared__ unsigned short Ptile[2][32][264];  // 33.8 KB
  __shared__ float Rtile[4][32][68];            // 34.8 KB partial PV
  __shared__ float invS[32];                    // total ~132 KB

  const int tid = threadIdx.x, lane = tid & 63, wave = tid >> 6;
  const int l15 = lane & 15, quad = lane >> 4;
  const int bx = blockIdx.x;
  const int qb = (bx & 1) ? (63 - (bx >> 1)) : (bx >> 1);  // heavy+light mix
  const int h = blockIdx.y, q0 = qb * 32, col0 = h * CHD;
  const int g0 = q0 + wave;                   // wave's row in group A (0..15)
  const int g1 = q0 + 16 + wave;              // wave's row in group B (16..31)
  const int ntiles = (q0 + 287) >> 8;         // 256-col tiles covering 0..q0+31
  const int rmax = q0 + 31;                   // last valid column in this block

  // A-frags for both row groups: m=l15, k=kb*32+quad*8+j [m89/m91 layout]
  short8 a0h[2], a0l[2], a1h[2], a1l[2];
  {
    const size_t qbA = (size_t)(q0 + l15) * CD + col0 + quad * 8;
    const size_t qbB = (size_t)(q0 + 16 + l15) * CD + col0 + quad * 8;
#pragma unroll
    for (int kb = 0; kb < 2; kb++) {
      a0h[kb] = *reinterpret_cast<const short8*>(qh + qbA + kb * 32);
      a0l[kb] = *reinterpret_cast<const short8*>(ql + qbA + kb * 32);
      a1h[kb] = *reinterpret_cast<const short8*>(qh + qbB + kb * 32);
      a1l[kb] = *reinterpret_cast<const short8*>(ql + qbB + kb * 32);
    }
  }

  f32x32 s0, s1;
#pragma unroll
  for (int t = 0; t < 32; t++) { s0[t] = NEGS; s1[t] = NEGS; }

  // ---- Phase 1: scores (both row groups share the wave's K B-frag) ----
#pragma unroll
  for (int jt = 0; jt < 8; jt++) {
    if (jt < ntiles) {                        // WG-uniform
      const int j0 = jt * 256;
      const int buf = jt & 1;
      if (j0 + 16 * wave <= rmax) {           // wave-uniform causal-tail skip
        const size_t kbase = (size_t)(j0 + 16 * wave + l15) * CD + col0 + quad * 8;
        f32x4 c0 = {0.f, 0.f, 0.f, 0.f};
        f32x4 c1 = {0.f, 0.f, 0.f, 0.f};
#pragma unroll
        for (int kb = 0; kb < 2; kb++) {
          const short8 b_h = *reinterpret_cast<const short8*>(kh + kbase + kb * 32);
          const short8 b_l = *reinterpret_cast<const short8*>(kl + kbase + kb * 32);
          c0 = __builtin_amdgcn_mfma_f32_16x16x32_bf16(a0l[kb], b_l, c0, 0, 0, 0);
          c0 = __builtin_amdgcn_mfma_f32_16x16x32_bf16(a0h[kb], b_l, c0, 0, 0, 0);
          c0 = __builtin_amdgcn_mfma_f32_16x16x32_bf16(a0l[kb], b_h, c0, 0, 0, 0);
          c0 = __builtin_amdgcn_mfma_f32_16x16x32_bf16(a0h[kb], b_h, c0, 0, 0, 0);
          c1 = __builtin_amdgcn_mfma_f32_16x16x32_bf16(a1l[kb], b_l, c1, 0, 0, 0);
          c1 = __builtin_amdgcn_mfma_f32_16x16x32_bf16(a1h[kb], b_l, c1, 0, 0, 0);
          c1 = __builtin_amdgcn_mfma_f32_16x16x32_bf16(a1l[kb], b_h, c1, 0, 0, 0);
          c1 = __builtin_amdgcn_mfma_f32_16x16x32_bf16(a1h[kb], b_h, c1, 0, 0, 0);
        }
        // C layout: col(seq) = 16*wave + l15, row(q) = quad*4 + r (+16 for B)
#pragma unroll
        for (int r = 0; r < 4; r++) {
          Stile[buf][quad * 4 + r][16 * wave + l15] = c0[r];
          Stile[buf][16 + quad * 4 + r][16 * wave + l15] = c1[r];
        }
      }
      __syncthreads();
      // Gather MY rows: lane ll owns cols j0 + 64*tt + ll (2-way = free)
#pragma unroll
      for (int tt = 0; tt < 4; tt++) {
        const int col = j0 + 64 * tt + lane;
        if (j0 + 64 * tt <= g0) {             // wave-uniform group-valid check
          const float v = Stile[buf][wave][64 * tt + lane] * 0.125f;  // exact
          s0[jt * 4 + tt] = (col <= g0) ? v : NEGS;
        }
        if (j0 + 64 * tt <= g1) {
          const float v = Stile[buf][wave + 16][64 * tt + lane] * 0.125f;
          s1[jt * 4 + tt] = (col <= g1) ? v : NEGS;
        }
      }
      // no trailing barrier: next scatter targets the other buffer
    }
  }

  // ---- Phase 2: fused 2-row Michelot per wave (32 rows in parallel) ----
  float inv0, inv1;
  entmax_pair(s0, s1, g0, g1, inv0, inv1);
  if (lane == 0) { invS[wave] = inv0; invS[wave + 16] = inv1; }

  // ---- Phase 3: P @ V (wave = (kgroup, dim-block); both row groups) ----
  f32x4 acc0 = {0.f, 0.f, 0.f, 0.f};
  f32x4 acc1 = {0.f, 0.f, 0.f, 0.f};
  const int db = wave & 3, kcg = wave >> 2;
#pragma unroll
  for (int jt = 0; jt < 8; jt++) {
    if (jt < ntiles) {
      const int j0 = jt * 256;
      const int buf = jt & 1;
      // write MY rows' p for this tile (bf16; zeros where masked)
#pragma unroll
      for (int tt = 0; tt < 4; tt++)
        if (j0 + 64 * tt <= rmax) {           // skip groups no chunk reads
          Ptile[buf][wave][64 * tt + lane] = bf16_bits(s0[jt * 4 + tt]);
          Ptile[buf][wave + 16][64 * tt + lane] = bf16_bits(s1[jt * 4 + tt]);
        }
      __syncthreads();
      const size_t vrowbase =
          (size_t)(col0 + 16 * db + l15) * CL + j0;
#pragma unroll
      for (int t2 = 0; t2 < 2; t2++) {
        const int kc = 2 * kcg + t2;  // this wave's K-chunk of 32
        if (j0 + kc * 32 <= rmax) {           // wave-uniform causal-tail skip
          const short8 pa0 =
              *reinterpret_cast<const short8*>(&Ptile[buf][l15][kc * 32 + quad * 8]);
          const short8 pa1 =
              *reinterpret_cast<const short8*>(&Ptile[buf][l15 + 16][kc * 32 + quad * 8]);
          const size_t vb = vrowbase + kc * 32 + quad * 8;
          const short8 vbh = *reinterpret_cast<const short8*>(vhT + vb);
          const short8 vbl = *reinterpret_cast<const short8*>(vlT + vb);
          acc0 = __builtin_amdgcn_mfma_f32_16x16x32_bf16(pa0, vbl, acc0, 0, 0, 0);
          acc0 = __builtin_amdgcn_mfma_f32_16x16x32_bf16(pa0, vbh, acc0, 0, 0, 0);
          acc1 = __builtin_amdgcn_mfma_f32_16x16x32_bf16(pa1, vbl, acc1, 0, 0, 0);
          acc1 = __builtin_amdgcn_mfma_f32_16x16x32_bf16(pa1, vbh, acc1, 0, 0, 0);
        }
      }
      // no trailing barrier: next P-write targets the other buffer
    }
  }

  // ---- Cross-wave K-group reduce + epilogue (32 rows) ----
#pragma unroll
  for (int r = 0; r < 4; r++) {
    Rtile[kcg][quad * 4 + r][db * 16 + l15] = acc0[r];
    Rtile[kcg][16 + quad * 4 + r][db * 16 + l15] = acc1[r];
  }
  __syncthreads();
  if (wave < 4) {  // wave u handles dim-block u for all 32 rows
#pragma unroll
    for (int r = 0; r < 8; r++) {
      const int row = quad * 8 + r;
      float o = (Rtile[0][row][wave * 16 + l15] + Rtile[1][row][wave * 16 + l15]) +
                (Rtile[2][row][wave * 16 + l15] + Rtile[3][row][wave * 16 + l15]);
      o *= invS[row];
      short sh, sl;
      split1(o, sh, sl);
      const size_t oidx = (size_t)(q0 + row) * CD + col0 + wave * 16 + l15;
      oh[oidx] = sh;
      ol[oidx] = sl;
    }
  }
}

extern "C" void kernel_launch(void* const* d_in, const int* in_sizes, int n_in,
                              void* d_out, int out_size, void* d_ws, size_t ws_size,
                              hipStream_t stream) {
  const float* x  = (const float*)d_in[0];
  const float* Wq = (const float*)d_in[1];
  const float* Wk = (const float*)d_in[2];
  const float* Wv = (const float*)d_in[3];
  const float* Wo = (const float*)d_in[4];
  float* out = (float*)d_out;

  // Workspace layout (56 MB total)
  char* ws = (char*)d_ws;
  short* xh  = (short*)(ws + (0ull  << 20));
  short* xl  = (short*)(ws + (4ull  << 20));
  short* wqh = (short*)(ws + (8ull  << 20));
  short* wql = (short*)(ws + (10ull << 20));
  short* wkh = (short*)(ws + (12ull << 20));
  short* wkl = (short*)(ws + (14ull << 20));
  short* wvh = (short*)(ws + (16ull << 20));
  short* wvl = (short*)(ws + (18ull << 20));
  short* woh = (short*)(ws + (20ull << 20));
  short* wol = (short*)(ws + (22ull << 20));
  short* qhp = (short*)(ws + (24ull << 20));
  short* qlp = (short*)(ws + (28ull << 20));
  short* khp = (short*)(ws + (32ull << 20));
  short* klp = (short*)(ws + (36ull << 20));
  short* vhT = (short*)(ws + (40ull << 20));
  short* vlT = (short*)(ws + (44ull << 20));
  short* ohp = (short*)(ws + (48ull << 20));
  short* olp = (short*)(ws + (52ull << 20));

  split_all<<<6144, 256, 0, stream>>>(x, Wq, Wk, Wv, Wo,
                                      xh, xl, wqh, wql, wkh, wkl,
                                      wvh, wvl, woh, wol);

  // Fused QKV: grid.x = 24, sel = x>>3 -> q/k planes row-major, vT transposed
  gemm128_split<<<dim3(24, CL / 128), 256, 0, stream>>>(
      xh, xl, wqh, wql, wkh, wkl, wvh, wvl,
      qhp, qlp, khp, klp, vhT, vlT, nullptr, 0);

  attn32<<<dim3(CL / 32, CH), 1024, 0, stream>>>(
      qhp, qlp, khp, klp, vhT, vlT, ohp, olp);

  // Wo: grid.x = 8 (sel = 0), fp32 out
  gemm128_split<<<dim3(8, CL / 128), 256, 0, stream>>>(
      ohp, olp, woh, wol, woh, wol, woh, wol,
      ohp, olp, ohp, olp, ohp, olp, out, 1);
}

// Round 13
// 386.844 us; speedup vs baseline: 1.4774x; 1.0509x over previous
//
#include <hip/hip_runtime.h>
#include <hip/hip_bf16.h>

// Problem constants (B=1)
#define CL 2048   // sequence length
#define CD 1024   // hidden
#define CH 16     // heads
#define CHD 64    // head dim
#define NEGS -1e30f

typedef __attribute__((ext_vector_type(8))) short short8;  // 8 x bf16 frag
typedef __attribute__((ext_vector_type(4))) float f32x4;
// One row of scores: 32 regs, static indices everywhere.
typedef __attribute__((ext_vector_type(32))) float f32x32;

// DPP wave reductions (R16; measured R9 ~-8us, kept: strictly better).
template <int CTRL>
__device__ __forceinline__ float dpp_add_step(float x) {
  int v = __builtin_amdgcn_update_dpp(0, __builtin_bit_cast(int, x),
                                      CTRL, 0xf, 0xf, true);
  return x + __builtin_bit_cast(float, v);
}
template <int CTRL>
__device__ __forceinline__ float dpp_max_step(float x) {
  int v = __builtin_amdgcn_update_dpp((int)0xff800000, __builtin_bit_cast(int, x),
                                      CTRL, 0xf, 0xf, false);
  return fmaxf(x, __builtin_bit_cast(float, v));
}
__device__ __forceinline__ float wave_sum(float x) {
  x = dpp_add_step<0x111>(x);  // row_shr:1
  x = dpp_add_step<0x112>(x);  // row_shr:2
  x = dpp_add_step<0x114>(x);  // row_shr:4
  x = dpp_add_step<0x118>(x);  // row_shr:8
  x = dpp_add_step<0x142>(x);  // row_bcast:15
  x = dpp_add_step<0x143>(x);  // row_bcast:31
  return __builtin_bit_cast(float,
      __builtin_amdgcn_readlane(__builtin_bit_cast(int, x), 63));
}
__device__ __forceinline__ float wave_max(float x) {
  x = dpp_max_step<0x111>(x);
  x = dpp_max_step<0x112>(x);
  x = dpp_max_step<0x114>(x);
  x = dpp_max_step<0x118>(x);
  x = dpp_max_step<0x142>(x);
  x = dpp_max_step<0x143>(x);
  return __builtin_bit_cast(float,
      __builtin_amdgcn_readlane(__builtin_bit_cast(int, x), 63));
}

__device__ __forceinline__ void split1(float v, short& h, short& l) {
  __hip_bfloat16 bh = __float2bfloat16(v);
  __hip_bfloat16 bl = __float2bfloat16(v - __bfloat162float(bh));
  h = __builtin_bit_cast(short, bh);
  l = __builtin_bit_cast(short, bl);
}
__device__ __forceinline__ unsigned short bf16_bits(float v) {
  __hip_bfloat16 b = __float2bfloat16(v);
  return (unsigned short)__builtin_bit_cast(short, b);
}

// ---- depth-5 tree helpers over f32x32 (one-shot; unguarded on purpose:
// relu MUST zero the causally-masked elems for the Ptile write) ----
__device__ __forceinline__ float tree_sum_valid(const f32x32& s) {
  float t[8];
#pragma unroll
  for (int i = 0; i < 8; i++) {
    const float a = s[i]      > -1e29f ? s[i]      : 0.f;
    const float b = s[i + 8]  > -1e29f ? s[i + 8]  : 0.f;
    const float c = s[i + 16] > -1e29f ? s[i + 16] : 0.f;
    const float d = s[i + 24] > -1e29f ? s[i + 24] : 0.f;
    t[i] = (a + b) + (c + d);
  }
#pragma unroll
  for (int i = 0; i < 4; i++) t[i] += t[i + 4];
  t[0] += t[2]; t[1] += t[3];
  return t[0] + t[1];
}
__device__ __forceinline__ float tree_max(const f32x32& s) {
  float t[8];
#pragma unroll
  for (int i = 0; i < 8; i++)
    t[i] = fmaxf(fmaxf(s[i], s[i + 8]), fmaxf(s[i + 16], s[i + 24]));
#pragma unroll
  for (int i = 0; i < 4; i++) t[i] = fmaxf(t[i], t[i + 4]);
  return fmaxf(fmaxf(t[0], t[2]), fmaxf(t[1], t[3]));
}
__device__ __forceinline__ float relu_store_sum(f32x32& s, float ts_) {
  float t[8];
#pragma unroll
  for (int i = 0; i < 8; i++) {
    float a = s[i] - ts_;      a = a > 0.f ? a : 0.f;
    float b = s[i + 8] - ts_;  b = b > 0.f ? b : 0.f;
    float c = s[i + 16] - ts_; c = c > 0.f ? c : 0.f;
    float d = s[i + 24] - ts_; d = d > 0.f ? d : 0.f;
    s[i] = a; s[i + 8] = b; s[i + 16] = c; s[i + 24] = d;
    t[i] = (a + b) + (c + d);
  }
#pragma unroll
  for (int i = 0; i < 4; i++) t[i] += t[i + 4];
  t[0] += t[2]; t[1] += t[3];
  return t[0] + t[1];
}

// R19/R20 fused 2-row Michelot (measured R12: attn 318->235us with the
// 32-row/2-per-wave structure). Ballot count on scalar pipe; it-invariant
// wave-uniform causal guards; per-row gated tau/cnt updates; freeze-stable.
__device__ __forceinline__ void entmax_pair(f32x32& s0, f32x32& s1,
                                            int g0, int g1,
                                            float& inv0, float& inv1) {
  const float ss0 = wave_sum(tree_sum_valid(s0));
  const float m0  = wave_max(tree_max(s0));
  const float ss1 = wave_sum(tree_sum_valid(s1));
  const float m1  = wave_max(tree_max(s1));
  float tau0 = m0 - 1.000001f, tau1 = m1 - 1.000001f;
  int cnt0 = 0, cnt1 = 0;
  for (int it = 0; it < 64; it++) {
    float sum0 = 0.f, sum1 = 0.f;
    int c0 = 0, c1 = 0;
#pragma unroll
    for (int jt = 0; jt < 8; jt++) {
      if (jt * 256 <= g0) {             // wave-uniform causal guard (row 0)
#pragma unroll
        for (int tt = 0; tt < 4; tt++) {
          const float a = s0[jt * 4 + tt];
          const bool pr = a > tau0;
          sum0 += pr ? a : 0.f;
          c0 += (int)__popcll(__ballot(pr));
        }
      }
      if (jt * 256 <= g1) {             // wave-uniform causal guard (row 1)
#pragma unroll
        for (int tt = 0; tt < 4; tt++) {
          const float a = s1[jt * 4 + tt];
          const bool pr = a > tau1;
          sum1 += pr ? a : 0.f;
          c1 += (int)__popcll(__ballot(pr));
        }
      }
    }
    const float cs0 = wave_sum(sum0);   // two independent DPP chains (ILP)
    const float cs1 = wave_sum(sum1);
    const bool st0 = (c0 == cnt0), st1 = (c1 == cnt1);
    if (st0 && st1) break;
    if (!st0) { cnt0 = c0; tau0 = (cs0 - 1.f) / (float)c0; }
    if (!st1) { cnt1 = c1; tau1 = (cs1 - 1.f) / (float)c1; }
  }
  const float ts0 = (ss0 - 1.f) / (float)cnt0;
  const float ts1 = (ss1 - 1.f) / (float)cnt1;
  inv0 = 1.f / (wave_sum(relu_store_sum(s0, ts0)) + 1e-10f);
  inv1 = 1.f / (wave_sum(relu_store_sum(s1, ts1)) + 1e-10f);
}

// One fused split kernel: fp32 -> bf16 hi/lo planes for x and 4 weights.
__global__ __launch_bounds__(256) void split_all(
    const float* __restrict__ x,  const float* __restrict__ wq,
    const float* __restrict__ wk, const float* __restrict__ wv,
    const float* __restrict__ wo,
    short* __restrict__ xh,  short* __restrict__ xl,
    short* __restrict__ wqh, short* __restrict__ wql,
    short* __restrict__ wkh, short* __restrict__ wkl,
    short* __restrict__ wvh, short* __restrict__ wvl,
    short* __restrict__ woh, short* __restrict__ wol) {
  const int b = blockIdx.x;
  const float* src; short *dh, *dl; int i0;
  if      (b < 2048) { src = x;  dh = xh;  dl = xl;  i0 = b; }
  else if (b < 3072) { src = wq; dh = wqh; dl = wql; i0 = b - 2048; }
  else if (b < 4096) { src = wk; dh = wkh; dl = wkl; i0 = b - 3072; }
  else if (b < 5120) { src = wv; dh = wvh; dl = wvl; i0 = b - 4096; }
  else               { src = wo; dh = woh; dl = wol; i0 = b - 5120; }
  const int i = i0 * 256 + threadIdx.x;
  const float4 v = reinterpret_cast<const float4*>(src)[i];
  const float vv[4] = {v.x, v.y, v.z, v.w};
  short hh[4], ll[4];
#pragma unroll
  for (int e = 0; e < 4; e++) split1(vv[e], hh[e], ll[e]);
  reinterpret_cast<short4*>(dh)[i] = make_short4(hh[0], hh[1], hh[2], hh[3]);
  reinterpret_cast<short4*>(dl)[i] = make_short4(ll[0], ll[1], ll[2], ll[3]);
}

// C[2048,1024] = (Ah+Al) * (B?h+B?l)^T via 3-term split-bf16 MFMA.
// 128x128 tile/WG. R21: BK=64 — two 32-K sub-steps per barrier pair (16
// sync-pairs instead of 32; the compiler's pre-barrier vmcnt/lgkmcnt drain is
// the known ~20% overhead of this structure). LDS 64KB (2 blocks/CU: 128<160).
// Frag regs unchanged: per-kb reload. Numerics BIT-IDENTICAL to BK=32 (same
// MFMA accumulation order over k). Lane-linear staging: LDS off = i*1024 +
// lane*16; global row = i*8 + (lane>>3), chunk = (lane&7)*8.
__global__ __launch_bounds__(256, 2) void gemm128_split(
    const short* __restrict__ Ah, const short* __restrict__ Al,
    const short* __restrict__ B0h, const short* __restrict__ B0l,
    const short* __restrict__ B1h, const short* __restrict__ B1l,
    const short* __restrict__ B2h, const short* __restrict__ B2l,
    short* __restrict__ O0h, short* __restrict__ O0l,
    short* __restrict__ O1h, short* __restrict__ O1l,
    short* __restrict__ O2h, short* __restrict__ O2l,
    float* __restrict__ Cf, int fp32out) {
  __shared__ short AhS[128][64], AlS[128][64], BhS[128][64], BlS[128][64];
  const int tid = threadIdx.x, lane = tid & 63, wave = tid >> 6;
  const int l15 = lane & 15, quad = lane >> 4;
  const int sel = blockIdx.x >> 3, nb = blockIdx.x & 7;
  const short* Bh = sel == 0 ? B0h : (sel == 1 ? B1h : B2h);
  const short* Bl = sel == 0 ? B0l : (sel == 1 ? B1l : B2l);
  const int m0 = blockIdx.y * 128, n0 = nb * 128;
  const int wm = (wave >> 1) * 64, wn = (wave & 1) * 64;

  f32x4 acc[4][4];
#pragma unroll
  for (int i = 0; i < 4; i++)
#pragma unroll
    for (int j = 0; j < 4; j++) acc[i][j] = {0.f, 0.f, 0.f, 0.f};

  const short* gsrc = wave == 0 ? Ah : wave == 1 ? Al : wave == 2 ? Bh : Bl;
  short(*ldst)[64] = wave == 0 ? AhS : wave == 1 ? AlS : wave == 2 ? BhS : BlS;
  const int srow0 = (wave < 2) ? m0 : n0;
  const int sr = lane >> 3, skc = (lane & 7) * 8;  // row-in-8, 16B chunk

  for (int k0 = 0; k0 < CD; k0 += 64) {
    // 16 x global_load_lds_dwordx4: wave-uniform LDS base + lane*16.
#pragma unroll
    for (int i = 0; i < 16; i++) {
      const short* gp =
          gsrc + (size_t)(srow0 + i * 8 + sr) * CD + k0 + skc;
      __builtin_amdgcn_global_load_lds(
          (const __attribute__((address_space(1))) void*)gp,
          (__attribute__((address_space(3))) void*)((char*)&ldst[0][0] + i * 1024),
          16, 0, 0);
    }
    __syncthreads();
#pragma unroll
    for (int kb = 0; kb < 2; kb++) {
      short8 a_h[4], a_l[4], b_h[4], b_l[4];
#pragma unroll
      for (int i = 0; i < 4; i++) {
        a_h[i] = *reinterpret_cast<const short8*>(&AhS[wm + i * 16 + l15][kb * 32 + quad * 8]);
        a_l[i] = *reinterpret_cast<const short8*>(&AlS[wm + i * 16 + l15][kb * 32 + quad * 8]);
        b_h[i] = *reinterpret_cast<const short8*>(&BhS[wn + i * 16 + l15][kb * 32 + quad * 8]);
        b_l[i] = *reinterpret_cast<const short8*>(&BlS[wn + i * 16 + l15][kb * 32 + quad * 8]);
      }
#pragma unroll
      for (int im = 0; im < 4; im++)
#pragma unroll
        for (int in = 0; in < 4; in++) {
          acc[im][in] = __builtin_amdgcn_mfma_f32_16x16x32_bf16(a_h[im], b_l[in], acc[im][in], 0, 0, 0);
          acc[im][in] = __builtin_amdgcn_mfma_f32_16x16x32_bf16(a_l[im], b_h[in], acc[im][in], 0, 0, 0);
          acc[im][in] = __builtin_amdgcn_mfma_f32_16x16x32_bf16(a_h[im], b_h[in], acc[im][in], 0, 0, 0);
        }
    }
    __syncthreads();
  }

#pragma unroll
  for (int im = 0; im < 4; im++)
#pragma unroll
    for (int in = 0; in < 4; in++)
#pragma unroll
      for (int r = 0; r < 4; r++) {
        const int mr = m0 + wm + im * 16 + quad * 4 + r;
        const int nc = n0 + wn + in * 16 + l15;
        const float val = acc[im][in][r];
        if (fp32out) {
          Cf[(size_t)mr * CD + nc] = val;
        } else {
          short sh, sl;
          split1(val, sh, sl);
          if (sel == 0) {
            O0h[(size_t)mr * CD + nc] = sh; O0l[(size_t)mr * CD + nc] = sl;
          } else if (sel == 1) {
            O1h[(size_t)mr * CD + nc] = sh; O1l[(size_t)mr * CD + nc] = sl;
          } else {  // vT[dim][seq]
            O2h[(size_t)nc * CL + mr] = sh; O2l[(size_t)nc * CL + mr] = sl;
          }
        }
      }
}

// R21: attn32 (R12-measured 235us) with a qb0 offset so the launcher can
// split the grid into a LIGHT half (qb 0..31) and a HEAVY half (qb 32..63).
// Instrumentation: the two dispatches appear separately in the counter
// table; duration ratio B/A decomposes tile-proportional work (phases 1/3)
// vs fixed/Michelot cost. Heavy+light interleave kept WITHIN each half for
// round balance. Structure unchanged from the measured kernel.
__global__ __launch_bounds__(1024, 4) void attn32(
    const short* __restrict__ qh, const short* __restrict__ ql,
    const short* __restrict__ kh, const short* __restrict__ kl,
    const short* __restrict__ vhT, const short* __restrict__ vlT,
    short* __restrict__ oh, short* __restrict__ ol, int qb0) {
  __shared__ float Stile[2][32][260];           // 66.6 KB
  __shared__ unsigned short Ptile[2][32][264];  // 33.8 KB
  __shared__ float Rtile[4][32][68];            // 34.8 KB partial PV
  __shared__ float invS[32];                    // total ~132 KB

  const int tid = threadIdx.x, lane = tid & 63, wave = tid >> 6;
  const int l15 = lane & 15, quad = lane >> 4;
  const int bx = blockIdx.x;                    // 0..31 within this half
  const int qb = qb0 + ((bx & 1) ? (31 - (bx >> 1)) : (bx >> 1));
  const int h = blockIdx.y, q0 = qb * 32, col0 = h * CHD;
  const int g0 = q0 + wave;                   // wave's row in group A (0..15)
  const int g1 = q0 + 16 + wave;              // wave's row in group B (16..31)
  const int ntiles = (q0 + 287) >> 8;         // 256-col tiles covering 0..q0+31
  const int rmax = q0 + 31;                   // last valid column in this block

  // A-frags for both row groups: m=l15, k=kb*32+quad*8+j [m89/m91 layout]
  short8 a0h[2], a0l[2], a1h[2], a1l[2];
  {
    const size_t qbA = (size_t)(q0 + l15) * CD + col0 + quad * 8;
    const size_t qbB = (size_t)(q0 + 16 + l15) * CD + col0 + quad * 8;
#pragma unroll
    for (int kb = 0; kb < 2; kb++) {
      a0h[kb] = *reinterpret_cast<const short8*>(qh + qbA + kb * 32);
      a0l[kb] = *reinterpret_cast<const short8*>(ql + qbA + kb * 32);
      a1h[kb] = *reinterpret_cast<const short8*>(qh + qbB + kb * 32);
      a1l[kb] = *reinterpret_cast<const short8*>(ql + qbB + kb * 32);
    }
  }

  f32x32 s0, s1;
#pragma unroll
  for (int t = 0; t < 32; t++) { s0[t] = NEGS; s1[t] = NEGS; }

  // ---- Phase 1: scores (both row groups share the wave's K B-frag) ----
#pragma unroll
  for (int jt = 0; jt < 8; jt++) {
    if (jt < ntiles) {                        // WG-uniform
      const int j0 = jt * 256;
      const int buf = jt & 1;
      if (j0 + 16 * wave <= rmax) {           // wave-uniform causal-tail skip
        const size_t kbase = (size_t)(j0 + 16 * wave + l15) * CD + col0 + quad * 8;
        f32x4 c0 = {0.f, 0.f, 0.f, 0.f};
        f32x4 c1 = {0.f, 0.f, 0.f, 0.f};
#pragma unroll
        for (int kb = 0; kb < 2; kb++) {
          const short8 b_h = *reinterpret_cast<const short8*>(kh + kbase + kb * 32);
          const short8 b_l = *reinterpret_cast<const short8*>(kl + kbase + kb * 32);
          c0 = __builtin_amdgcn_mfma_f32_16x16x32_bf16(a0l[kb], b_l, c0, 0, 0, 0);
          c0 = __builtin_amdgcn_mfma_f32_16x16x32_bf16(a0h[kb], b_l, c0, 0, 0, 0);
          c0 = __builtin_amdgcn_mfma_f32_16x16x32_bf16(a0l[kb], b_h, c0, 0, 0, 0);
          c0 = __builtin_amdgcn_mfma_f32_16x16x32_bf16(a0h[kb], b_h, c0, 0, 0, 0);
          c1 = __builtin_amdgcn_mfma_f32_16x16x32_bf16(a1l[kb], b_l, c1, 0, 0, 0);
          c1 = __builtin_amdgcn_mfma_f32_16x16x32_bf16(a1h[kb], b_l, c1, 0, 0, 0);
          c1 = __builtin_amdgcn_mfma_f32_16x16x32_bf16(a1l[kb], b_h, c1, 0, 0, 0);
          c1 = __builtin_amdgcn_mfma_f32_16x16x32_bf16(a1h[kb], b_h, c1, 0, 0, 0);
        }
        // C layout: col(seq) = 16*wave + l15, row(q) = quad*4 + r (+16 for B)
#pragma unroll
        for (int r = 0; r < 4; r++) {
          Stile[buf][quad * 4 + r][16 * wave + l15] = c0[r];
          Stile[buf][16 + quad * 4 + r][16 * wave + l15] = c1[r];
        }
      }
      __syncthreads();
      // Gather MY rows: lane ll owns cols j0 + 64*tt + ll (2-way = free)
#pragma unroll
      for (int tt = 0; tt < 4; tt++) {
        const int col = j0 + 64 * tt + lane;
        if (j0 + 64 * tt <= g0) {             // wave-uniform group-valid check
          const float v = Stile[buf][wave][64 * tt + lane] * 0.125f;  // exact
          s0[jt * 4 + tt] = (col <= g0) ? v : NEGS;
        }
        if (j0 + 64 * tt <= g1) {
          const float v = Stile[buf][wave + 16][64 * tt + lane] * 0.125f;
          s1[jt * 4 + tt] = (col <= g1) ? v : NEGS;
        }
      }
      // no trailing barrier: next scatter targets the other buffer
    }
  }

  // ---- Phase 2: fused 2-row Michelot per wave (32 rows in parallel) ----
  float inv0, inv1;
  entmax_pair(s0, s1, g0, g1, inv0, inv1);
  if (lane == 0) { invS[wave] = inv0; invS[wave + 16] = inv1; }

  // ---- Phase 3: P @ V (wave = (kgroup, dim-block); both row groups) ----
  f32x4 acc0 = {0.f, 0.f, 0.f, 0.f};
  f32x4 acc1 = {0.f, 0.f, 0.f, 0.f};
  const int db = wave & 3, kcg = wave >> 2;
#pragma unroll
  for (int jt = 0; jt < 8; jt++) {
    if (jt < ntiles) {
      const int j0 = jt * 256;
      const int buf = jt & 1;
      // write MY rows' p for this tile (bf16; zeros where masked)
#pragma unroll
      for (int tt = 0; tt < 4; tt++)
        if (j0 + 64 * tt <= rmax) {           // skip groups no chunk reads
          Ptile[buf][wave][64 * tt + lane] = bf16_bits(s0[jt * 4 + tt]);
          Ptile[buf][wave + 16][64 * tt + lane] = bf16_bits(s1[jt * 4 + tt]);
        }
      __syncthreads();
      const size_t vrowbase =
          (size_t)(col0 + 16 * db + l15) * CL + j0;
#pragma unroll
      for (int t2 = 0; t2 < 2; t2++) {
        const int kc = 2 * kcg + t2;  // this wave's K-chunk of 32
        if (j0 + kc * 32 <= rmax) {           // wave-uniform causal-tail skip
          const short8 pa0 =
              *reinterpret_cast<const short8*>(&Ptile[buf][l15][kc * 32 + quad * 8]);
          const short8 pa1 =
              *reinterpret_cast<const short8*>(&Ptile[buf][l15 + 16][kc * 32 + quad * 8]);
          const size_t vb = vrowbase + kc * 32 + quad * 8;
          const short8 vbh = *reinterpret_cast<const short8*>(vhT + vb);
          const short8 vbl = *reinterpret_cast<const short8*>(vlT + vb);
          acc0 = __builtin_amdgcn_mfma_f32_16x16x32_bf16(pa0, vbl, acc0, 0, 0, 0);
          acc0 = __builtin_amdgcn_mfma_f32_16x16x32_bf16(pa0, vbh, acc0, 0, 0, 0);
          acc1 = __builtin_amdgcn_mfma_f32_16x16x32_bf16(pa1, vbl, acc1, 0, 0, 0);
          acc1 = __builtin_amdgcn_mfma_f32_16x16x32_bf16(pa1, vbh, acc1, 0, 0, 0);
        }
      }
      // no trailing barrier: next P-write targets the other buffer
    }
  }

  // ---- Cross-wave K-group reduce + epilogue (32 rows) ----
#pragma unroll
  for (int r = 0; r < 4; r++) {
    Rtile[kcg][quad * 4 + r][db * 16 + l15] = acc0[r];
    Rtile[kcg][16 + quad * 4 + r][db * 16 + l15] = acc1[r];
  }
  __syncthreads();
  if (wave < 4) {  // wave u handles dim-block u for all 32 rows
#pragma unroll
    for (int r = 0; r < 8; r++) {
      const int row = quad * 8 + r;
      float o = (Rtile[0][row][wave * 16 + l15] + Rtile[1][row][wave * 16 + l15]) +
                (Rtile[2][row][wave * 16 + l15] + Rtile[3][row][wave * 16 + l15]);
      o *= invS[row];
      short sh, sl;
      split1(o, sh, sl);
      const size_t oidx = (size_t)(q0 + row) * CD + col0 + wave * 16 + l15;
      oh[oidx] = sh;
      ol[oidx] = sl;
    }
  }
}

extern "C" void kernel_launch(void* const* d_in, const int* in_sizes, int n_in,
                              void* d_out, int out_size, void* d_ws, size_t ws_size,
                              hipStream_t stream) {
  const float* x  = (const float*)d_in[0];
  const float* Wq = (const float*)d_in[1];
  const float* Wk = (const float*)d_in[2];
  const float* Wv = (const float*)d_in[3];
  const float* Wo = (const float*)d_in[4];
  float* out = (float*)d_out;

  // Workspace layout (56 MB total)
  char* ws = (char*)d_ws;
  short* xh  = (short*)(ws + (0ull  << 20));
  short* xl  = (short*)(ws + (4ull  << 20));
  short* wqh = (short*)(ws + (8ull  << 20));
  short* wql = (short*)(ws + (10ull << 20));
  short* wkh = (short*)(ws + (12ull << 20));
  short* wkl = (short*)(ws + (14ull << 20));
  short* wvh = (short*)(ws + (16ull << 20));
  short* wvl = (short*)(ws + (18ull << 20));
  short* woh = (short*)(ws + (20ull << 20));
  short* wol = (short*)(ws + (22ull << 20));
  short* qhp = (short*)(ws + (24ull << 20));
  short* qlp = (short*)(ws + (28ull << 20));
  short* khp = (short*)(ws + (32ull << 20));
  short* klp = (short*)(ws + (36ull << 20));
  short* vhT = (short*)(ws + (40ull << 20));
  short* vlT = (short*)(ws + (44ull << 20));
  short* ohp = (short*)(ws + (48ull << 20));
  short* olp = (short*)(ws + (52ull << 20));

  split_all<<<6144, 256, 0, stream>>>(x, Wq, Wk, Wv, Wo,
                                      xh, xl, wqh, wql, wkh, wkl,
                                      wvh, wvl, woh, wol);

  // Fused QKV: grid.x = 24, sel = x>>3 -> q/k planes row-major, vT transposed
  gemm128_split<<<dim3(24, CL / 128), 256, 0, stream>>>(
      xh, xl, wqh, wql, wkh, wkl, wvh, wvl,
      qhp, qlp, khp, klp, vhT, vlT, nullptr, 0);

  // attn split: light half (qb 0..31) then heavy half (qb 32..63) —
  // separate dispatches so rocprof reports their durations independently.
  attn32<<<dim3(32, CH), 1024, 0, stream>>>(
      qhp, qlp, khp, klp, vhT, vlT, ohp, olp, 0);
  attn32<<<dim3(32, CH), 1024, 0, stream>>>(
      qhp, qlp, khp, klp, vhT, vlT, ohp, olp, 32);

  // Wo: grid.x = 8 (sel = 0), fp32 out
  gemm128_split<<<dim3(8, CL / 128), 256, 0, stream>>>(
      ohp, olp, woh, wol, woh, wol, woh, wol,
      ohp, olp, ohp, olp, ohp, olp, out, 1);
}